// Round 1
// baseline (400.483 us; speedup 1.0000x reference)
//
#include <hip/hip_runtime.h>
#include <hip/hip_bf16.h>
#include <cstdint>
#include <cstddef>

typedef __attribute__((ext_vector_type(4))) float f32x4;
typedef __attribute__((ext_vector_type(8))) short short8;

#define S_LEN 4096
#define D_DIM 1024
#define H_DIM 1024
#define B_SZ  16
#define M_TOT (B_SZ * S_LEN)  // 65536

// ---------- helpers ----------
__device__ __forceinline__ unsigned short f2bf(float f) {
  // round-to-nearest-even fp32 -> bf16 (finite inputs only)
  unsigned int u = __float_as_uint(f);
  u += 0x7fffu + ((u >> 16) & 1u);
  return (unsigned short)(u >> 16);
}

__device__ __forceinline__ void gload_lds16(void* lds, const void* g) {
  __builtin_amdgcn_global_load_lds(
      (const __attribute__((address_space(1))) unsigned int*)g,
      (__attribute__((address_space(3))) unsigned int*)lds, 16, 0, 0);
}

__device__ __forceinline__ float tanh_fast(float x) {
  // tanh(x) = 1 - 2/(1+e^{2x}); exp overflow/underflow saturate correctly
  return 1.0f - 2.0f / (1.0f + __expf(2.0f * x));
}

// ---------- kernel 1: Ws_w fp32 -> bf16 ----------
__global__ void cvt_w_kernel(const float* __restrict__ w,
                             unsigned short* __restrict__ o) {
  int i = (blockIdx.x * 256 + threadIdx.x) * 8;
  float4 v0 = *(const float4*)(w + i);
  float4 v1 = *(const float4*)(w + i + 4);
  union { unsigned short us[8]; short8 v; } pk;
  pk.us[0] = f2bf(v0.x); pk.us[1] = f2bf(v0.y);
  pk.us[2] = f2bf(v0.z); pk.us[3] = f2bf(v0.w);
  pk.us[4] = f2bf(v1.x); pk.us[5] = f2bf(v1.y);
  pk.us[6] = f2bf(v1.z); pk.us[7] = f2bf(v1.w);
  *(short8*)(o + i) = pk.v;
}

// ---------- kernel 2: c[b,h] = ht_k[b]·Wt_w[h] + Wt_b[h] + hm_k[b]·Wr_w[h] + Wr_b[h] ----------
__global__ void prep_c_kernel(const float* __restrict__ ht,
                              const float* __restrict__ hm,
                              const float* __restrict__ Wt_w,
                              const float* __restrict__ Wt_b,
                              const float* __restrict__ Wr_w,
                              const float* __restrict__ Wr_b,
                              float* __restrict__ cvec) {
  int gw = blockIdx.x * 4 + (threadIdx.x >> 6);  // wave id 0..16383
  int lane = threadIdx.x & 63;
  int b = gw >> 10;
  int h = gw & 1023;
  const float* a1 = ht + b * D_DIM;
  const float* w1 = Wt_w + (size_t)h * D_DIM;
  const float* a2 = hm + b * H_DIM;
  const float* w2 = Wr_w + (size_t)h * H_DIM;
  float acc = 0.f;
#pragma unroll
  for (int i = 0; i < 4; ++i) {
    int d = lane * 4 + i * 256;
    float4 x1 = *(const float4*)(a1 + d);
    float4 y1 = *(const float4*)(w1 + d);
    float4 x2 = *(const float4*)(a2 + d);
    float4 y2 = *(const float4*)(w2 + d);
    acc += x1.x * y1.x + x1.y * y1.y + x1.z * y1.z + x1.w * y1.w;
    acc += x2.x * y2.x + x2.y * y2.y + x2.z * y2.z + x2.w * y2.w;
  }
#pragma unroll
  for (int off = 32; off >= 1; off >>= 1) acc += __shfl_xor(acc, off);
  if (lane == 0) cvec[b * H_DIM + h] = acc + Wt_b[h] + Wr_b[h];
}

// ---------- kernel 3: fused GEMM + tanh + dot(We_w) -> partial scores ----------
// C[m][h] = hs[m]·Ws[h];  score_part[gy][m] = sum over this block's h-range of
// tanh(C + c[b,h]) * We_w[h]
__global__ __launch_bounds__(256) void score_gemm_kernel(
    const float* __restrict__ hs,
    const unsigned short* __restrict__ Wsb,
    const float* __restrict__ cvec,
    const float* __restrict__ We_w,
    float* __restrict__ score_part) {
  __shared__ __align__(16) unsigned short lA[128 * 64];  // 16 KB, swizzled
  __shared__ __align__(16) unsigned short lB[128 * 64];  // 16 KB, swizzled
  __shared__ float scorebuf[2][128];

  const int tid = threadIdx.x;
  const int lane = tid & 63;
  const int wave = tid >> 6;
  const int wr = wave >> 1;  // 0..1 : row half
  const int wc = wave & 1;   // 0..1 : col half
  const int mtile = blockIdx.x;  // 0..511
  const int gy = blockIdx.y;     // 0..1 (n-chunk group)
  const int m0 = mtile * 128;
  const int b = mtile >> 5;  // 32 m-tiles per batch row

  const int l15 = lane & 15;
  const int lg = lane >> 4;

  float rowsum[4][4];
#pragma unroll
  for (int i = 0; i < 4; ++i)
#pragma unroll
    for (int j = 0; j < 4; ++j) rowsum[i][j] = 0.f;

  for (int nc = gy * 4; nc < gy * 4 + 4; ++nc) {
    const int n0 = nc * 128;
    f32x4 acc[4][4];
#pragma unroll
    for (int i = 0; i < 4; ++i)
#pragma unroll
      for (int j = 0; j < 4; ++j) acc[i][j] = (f32x4){0.f, 0.f, 0.f, 0.f};

    for (int k0 = 0; k0 < D_DIM; k0 += 64) {
      // stage B tile (bf16) via async global->LDS; source pre-swizzled so that
      // LDS[row][slot] holds source chunk (slot ^ (row&7)); dest is linear.
#pragma unroll
      for (int r = 0; r < 4; ++r) {
        int s = tid + r * 256;
        int row = s >> 3, sl = s & 7;
        int src = sl ^ (row & 7);
        gload_lds16(&lB[s * 8], Wsb + (size_t)(n0 + row) * D_DIM + k0 + src * 8);
      }
      // stage A tile: load fp32, convert to bf16, swizzled ds_write
      float4 a0[4], a1[4];
#pragma unroll
      for (int r = 0; r < 4; ++r) {
        int s = tid + r * 256;
        int row = s >> 3, sl = s & 7;
        int src = sl ^ (row & 7);
        const float* ga = hs + (size_t)(m0 + row) * D_DIM + k0 + src * 8;
        a0[r] = *(const float4*)ga;
        a1[r] = *(const float4*)(ga + 4);
      }
#pragma unroll
      for (int r = 0; r < 4; ++r) {
        int s = tid + r * 256;
        union { unsigned short us[8]; short8 v; } pk;
        pk.us[0] = f2bf(a0[r].x); pk.us[1] = f2bf(a0[r].y);
        pk.us[2] = f2bf(a0[r].z); pk.us[3] = f2bf(a0[r].w);
        pk.us[4] = f2bf(a1[r].x); pk.us[5] = f2bf(a1[r].y);
        pk.us[6] = f2bf(a1[r].z); pk.us[7] = f2bf(a1[r].w);
        *(short8*)(&lA[s * 8]) = pk.v;
      }
      __syncthreads();
      // fragments + MFMA (16x16x32 bf16)
#pragma unroll
      for (int kf = 0; kf < 2; ++kf) {
        short8 af[4], bfr[4];
        int cgrp = kf * 4 + lg;
#pragma unroll
        for (int mi = 0; mi < 4; ++mi) {
          int row = wr * 64 + mi * 16 + l15;
          af[mi] = *(const short8*)&lA[row * 64 + (cgrp ^ (row & 7)) * 8];
        }
#pragma unroll
        for (int ni = 0; ni < 4; ++ni) {
          int row = wc * 64 + ni * 16 + l15;
          bfr[ni] = *(const short8*)&lB[row * 64 + (cgrp ^ (row & 7)) * 8];
        }
#pragma unroll
        for (int mi = 0; mi < 4; ++mi)
#pragma unroll
          for (int ni = 0; ni < 4; ++ni)
            acc[mi][ni] = __builtin_amdgcn_mfma_f32_16x16x32_bf16(
                af[mi], bfr[ni], acc[mi][ni], 0, 0, 0);
      }
      __syncthreads();
    }
    // epilogue for this n-chunk: tanh(acc + c)·We_w, accumulate per-row
#pragma unroll
    for (int ni = 0; ni < 4; ++ni) {
      int h = n0 + wc * 64 + ni * 16 + l15;
      float ch = cvec[b * H_DIM + h];
      float wh = We_w[h];
#pragma unroll
      for (int mi = 0; mi < 4; ++mi)
#pragma unroll
        for (int r2 = 0; r2 < 4; ++r2)
          rowsum[mi][r2] += tanh_fast(acc[mi][ni][r2] + ch) * wh;
    }
  }
  // reduce across the 16 column-lanes (rows live in lane>>4 groups)
#pragma unroll
  for (int mi = 0; mi < 4; ++mi)
#pragma unroll
    for (int r2 = 0; r2 < 4; ++r2) {
      float v = rowsum[mi][r2];
      v += __shfl_xor(v, 1);
      v += __shfl_xor(v, 2);
      v += __shfl_xor(v, 4);
      v += __shfl_xor(v, 8);
      rowsum[mi][r2] = v;
    }
  if (l15 == 0) {
#pragma unroll
    for (int mi = 0; mi < 4; ++mi)
#pragma unroll
      for (int r2 = 0; r2 < 4; ++r2)
        scorebuf[wc][wr * 64 + mi * 16 + lg * 4 + r2] = rowsum[mi][r2];
  }
  __syncthreads();
  if (tid < 128) {
    score_part[(size_t)gy * M_TOT + m0 + tid] =
        scorebuf[0][tid] + scorebuf[1][tid];
  }
}

// ---------- kernel 4: softmax over S with rel-position bias ----------
__global__ void softmax_kernel(const float* __restrict__ part,
                               const int* __restrict__ hs_i,
                               const int* __restrict__ ht_i,
                               const float* __restrict__ emb,
                               const float* __restrict__ lam,
                               float* __restrict__ wout) {
  int b = blockIdx.x;
  int tid = threadIdx.x;
  float lam0 = lam[0], lam1 = lam[1], lam2 = lam[2];
  int tk = ht_i[b];
  float xs[16];
  float mx = -1e30f;
#pragma unroll
  for (int i = 0; i < 16; ++i) {
    int s = tid + i * 256;
    size_t m = (size_t)b * S_LEN + s;
    float x = part[m] + part[M_TOT + m];
    int idx = hs_i[m] * 512 + tk;
    const float* e = emb + (size_t)idx * 3;
    x += e[0] * lam0 + e[1] * lam1 + e[2] * lam2;
    xs[i] = x;
    mx = fmaxf(mx, x);
  }
  __shared__ float redm[4];
  __shared__ float reds[4];
#pragma unroll
  for (int off = 32; off >= 1; off >>= 1) mx = fmaxf(mx, __shfl_xor(mx, off));
  if ((tid & 63) == 0) redm[tid >> 6] = mx;
  __syncthreads();
  mx = fmaxf(fmaxf(redm[0], redm[1]), fmaxf(redm[2], redm[3]));
  float sum = 0.f;
#pragma unroll
  for (int i = 0; i < 16; ++i) {
    xs[i] = __expf(xs[i] - mx);
    sum += xs[i];
  }
#pragma unroll
  for (int off = 32; off >= 1; off >>= 1) sum += __shfl_xor(sum, off);
  if ((tid & 63) == 0) reds[tid >> 6] = sum;
  __syncthreads();
  sum = reds[0] + reds[1] + reds[2] + reds[3];
  float inv = 1.0f / sum;
#pragma unroll
  for (int i = 0; i < 16; ++i)
    wout[(size_t)b * S_LEN + tid + i * 256] = xs[i] * inv;
}

// ---------- kernel 5: u[b,d] = sum_s w[b,s]*hs[b,s,d] ----------
__global__ void wsum_kernel(const float* __restrict__ hs,
                            const float* __restrict__ w,
                            float* __restrict__ u) {
  int bx = blockIdx.x;  // 512: b = bx>>5, s-chunk = bx&31 (128 s each)
  int b = bx >> 5;
  int sc = bx & 31;
  int tid = threadIdx.x;
  int d = tid * 4;
  int s0 = sc * 128;
  const float* base = hs + ((size_t)b * S_LEN + s0) * D_DIM + d;
  const float* wrow = w + (size_t)b * S_LEN + s0;
  float4 acc = {0.f, 0.f, 0.f, 0.f};
#pragma unroll 4
  for (int i = 0; i < 128; ++i) {
    float ww = wrow[i];
    float4 v = *(const float4*)(base + (size_t)i * D_DIM);
    acc.x += ww * v.x;
    acc.y += ww * v.y;
    acc.z += ww * v.z;
    acc.w += ww * v.w;
  }
  atomicAdd(&u[b * D_DIM + d + 0], acc.x);
  atomicAdd(&u[b * D_DIM + d + 1], acc.y);
  atomicAdd(&u[b * D_DIM + d + 2], acc.z);
  atomicAdd(&u[b * D_DIM + d + 3], acc.w);
}

// ---------- kernel 6: alpha[b,h] = u[b]·Ws_w[h] + Ws_b[h] ----------
__global__ void alpha_kernel(const float* __restrict__ u,
                             const float* __restrict__ Ws_w,
                             const float* __restrict__ Ws_b,
                             float* __restrict__ out) {
  int gw = blockIdx.x * 4 + (threadIdx.x >> 6);
  int lane = threadIdx.x & 63;
  int b = gw >> 10;
  int h = gw & 1023;
  const float* ur = u + b * D_DIM;
  const float* wrow = Ws_w + (size_t)h * D_DIM;
  float acc = 0.f;
#pragma unroll
  for (int i = 0; i < 4; ++i) {
    int d = lane * 4 + i * 256;
    float4 x = *(const float4*)(ur + d);
    float4 y = *(const float4*)(wrow + d);
    acc += x.x * y.x + x.y * y.y + x.z * y.z + x.w * y.w;
  }
#pragma unroll
  for (int off = 32; off >= 1; off >>= 1) acc += __shfl_xor(acc, off);
  if (lane == 0) out[b * H_DIM + h] = acc + Ws_b[h];
}

extern "C" void kernel_launch(void* const* d_in, const int* in_sizes, int n_in,
                              void* d_out, int out_size, void* d_ws,
                              size_t ws_size, hipStream_t stream) {
  const float* hs = (const float*)d_in[0];
  const float* ht_k = (const float*)d_in[1];
  const float* hm_k = (const float*)d_in[2];
  const float* Ws_w = (const float*)d_in[3];
  const float* Ws_b = (const float*)d_in[4];
  const float* Wt_w = (const float*)d_in[5];
  const float* Wt_b = (const float*)d_in[6];
  const float* Wr_w = (const float*)d_in[7];
  const float* Wr_b = (const float*)d_in[8];
  const float* We_w = (const float*)d_in[9];
  // We_b (d_in[10]) is a constant shift -> softmax-invariant, unused
  const float* emb = (const float*)d_in[11];
  const float* lam = (const float*)d_in[12];
  const int* hs_i = (const int*)d_in[13];
  const int* ht_i = (const int*)d_in[14];
  float* out = (float*)d_out;

  char* ws = (char*)d_ws;
  unsigned short* Wsb = (unsigned short*)(ws);                  // 2 MB
  float* cvec = (float*)(ws + 2097152);                         // 64 KB
  float* part = (float*)(ws + 2097152 + 65536);                 // 512 KB
  float* wgt = (float*)(ws + 2097152 + 65536 + 524288);         // 256 KB
  float* u = (float*)(ws + 2097152 + 65536 + 524288 + 262144);  // 64 KB

  cvt_w_kernel<<<512, 256, 0, stream>>>(Ws_w, Wsb);
  prep_c_kernel<<<4096, 256, 0, stream>>>(ht_k, hm_k, Wt_w, Wt_b, Wr_w, Wr_b,
                                          cvec);
  dim3 g2(512, 2);
  score_gemm_kernel<<<g2, 256, 0, stream>>>(hs, Wsb, cvec, We_w, part);
  softmax_kernel<<<16, 256, 0, stream>>>(part, hs_i, ht_i, emb, lam, wgt);
  hipMemsetAsync(u, 0, B_SZ * D_DIM * sizeof(float), stream);
  wsum_kernel<<<512, 256, 0, stream>>>(hs, wgt, u);
  alpha_kernel<<<4096, 256, 0, stream>>>(u, Ws_w, Ws_b, out);
}

// Round 2
// 345.655 us; speedup vs baseline: 1.1586x; 1.1586x over previous
//
#include <hip/hip_runtime.h>
#include <hip/hip_bf16.h>
#include <cstdint>
#include <cstddef>

typedef __attribute__((ext_vector_type(4))) float f32x4;
typedef __attribute__((ext_vector_type(8))) short short8;

#define S_LEN 4096
#define D_DIM 1024
#define H_DIM 1024
#define B_SZ  16
#define M_TOT (B_SZ * S_LEN)  // 65536

// ---------- helpers ----------
__device__ __forceinline__ unsigned short f2bf(float f) {
  unsigned int u = __float_as_uint(f);
  u += 0x7fffu + ((u >> 16) & 1u);
  return (unsigned short)(u >> 16);
}

__device__ __forceinline__ void gload_lds16(void* lds, const void* g) {
  __builtin_amdgcn_global_load_lds(
      (const __attribute__((address_space(1))) unsigned int*)g,
      (__attribute__((address_space(3))) unsigned int*)lds, 16, 0, 0);
}

__device__ __forceinline__ float tanh_fast(float x) {
  return 1.0f - 2.0f / (1.0f + __expf(2.0f * x));
}

// ---------- kernel 0: hs fp32 -> bf16 (64M elems) ----------
__global__ void cvt_hs_kernel(const float* __restrict__ w,
                              unsigned short* __restrict__ o) {
  size_t i = ((size_t)blockIdx.x * 256 + threadIdx.x) * 8;
  float4 v0 = *(const float4*)(w + i);
  float4 v1 = *(const float4*)(w + i + 4);
  union { unsigned short us[8]; short8 v; } pk;
  pk.us[0] = f2bf(v0.x); pk.us[1] = f2bf(v0.y);
  pk.us[2] = f2bf(v0.z); pk.us[3] = f2bf(v0.w);
  pk.us[4] = f2bf(v1.x); pk.us[5] = f2bf(v1.y);
  pk.us[6] = f2bf(v1.z); pk.us[7] = f2bf(v1.w);
  *(short8*)(o + i) = pk.v;
}

// ---------- kernel 1: Ws_w fp32 -> bf16 ----------
__global__ void cvt_w_kernel(const float* __restrict__ w,
                             unsigned short* __restrict__ o) {
  int i = (blockIdx.x * 256 + threadIdx.x) * 8;
  float4 v0 = *(const float4*)(w + i);
  float4 v1 = *(const float4*)(w + i + 4);
  union { unsigned short us[8]; short8 v; } pk;
  pk.us[0] = f2bf(v0.x); pk.us[1] = f2bf(v0.y);
  pk.us[2] = f2bf(v0.z); pk.us[3] = f2bf(v0.w);
  pk.us[4] = f2bf(v1.x); pk.us[5] = f2bf(v1.y);
  pk.us[6] = f2bf(v1.z); pk.us[7] = f2bf(v1.w);
  *(short8*)(o + i) = pk.v;
}

// ---------- kernel 2: c[b,h] = ht_k[b]·Wt_w[h] + Wt_b[h] + hm_k[b]·Wr_w[h] + Wr_b[h] ----------
__global__ void prep_c_kernel(const float* __restrict__ ht,
                              const float* __restrict__ hm,
                              const float* __restrict__ Wt_w,
                              const float* __restrict__ Wt_b,
                              const float* __restrict__ Wr_w,
                              const float* __restrict__ Wr_b,
                              float* __restrict__ cvec) {
  int gw = blockIdx.x * 4 + (threadIdx.x >> 6);
  int lane = threadIdx.x & 63;
  int b = gw >> 10;
  int h = gw & 1023;
  const float* a1 = ht + b * D_DIM;
  const float* w1 = Wt_w + (size_t)h * D_DIM;
  const float* a2 = hm + b * H_DIM;
  const float* w2 = Wr_w + (size_t)h * H_DIM;
  float acc = 0.f;
#pragma unroll
  for (int i = 0; i < 4; ++i) {
    int d = lane * 4 + i * 256;
    float4 x1 = *(const float4*)(a1 + d);
    float4 y1 = *(const float4*)(w1 + d);
    float4 x2 = *(const float4*)(a2 + d);
    float4 y2 = *(const float4*)(w2 + d);
    acc += x1.x * y1.x + x1.y * y1.y + x1.z * y1.z + x1.w * y1.w;
    acc += x2.x * y2.x + x2.y * y2.y + x2.z * y2.z + x2.w * y2.w;
  }
#pragma unroll
  for (int off = 32; off >= 1; off >>= 1) acc += __shfl_xor(acc, off);
  if (lane == 0) cvec[b * H_DIM + h] = acc + Wt_b[h] + Wr_b[h];
}

// ---------- kernel 3 (fast path): fused GEMM + tanh + dot(We_w), bf16 A via global_load_lds ----------
__global__ __launch_bounds__(256) void score_gemm_kernel(
    const unsigned short* __restrict__ hsb,
    const unsigned short* __restrict__ Wsb,
    const float* __restrict__ cvec,
    const float* __restrict__ We_w,
    float* __restrict__ score_part) {
  __shared__ __align__(16) unsigned short lA[128 * 64];
  __shared__ __align__(16) unsigned short lB[128 * 64];
  __shared__ float scorebuf[2][128];

  const int tid = threadIdx.x;
  const int lane = tid & 63;
  const int wave = tid >> 6;
  const int wr = wave >> 1;
  const int wc = wave & 1;
  const int mtile = blockIdx.x;
  const int gy = blockIdx.y;
  const int m0 = mtile * 128;
  const int b = mtile >> 5;

  const int l15 = lane & 15;
  const int lg = lane >> 4;

  // precomputed swizzled staging indices
  const int s_row[4] = {(tid + 0) >> 3, (tid + 256) >> 3, (tid + 512) >> 3,
                        (tid + 768) >> 3};
  const int s_src[4] = {
      (tid & 7) ^ (s_row[0] & 7), (tid & 7) ^ (s_row[1] & 7),
      (tid & 7) ^ (s_row[2] & 7), (tid & 7) ^ (s_row[3] & 7)};

  float rowsum[4][4];
#pragma unroll
  for (int i = 0; i < 4; ++i)
#pragma unroll
    for (int j = 0; j < 4; ++j) rowsum[i][j] = 0.f;

  for (int nc = gy * 4; nc < gy * 4 + 4; ++nc) {
    const int n0 = nc * 128;
    f32x4 acc[4][4];
#pragma unroll
    for (int i = 0; i < 4; ++i)
#pragma unroll
      for (int j = 0; j < 4; ++j) acc[i][j] = (f32x4){0.f, 0.f, 0.f, 0.f};

    for (int k0 = 0; k0 < D_DIM; k0 += 64) {
#pragma unroll
      for (int r = 0; r < 4; ++r) {
        int s = tid + r * 256;
        gload_lds16(&lB[s * 8],
                    Wsb + (size_t)(n0 + s_row[r]) * D_DIM + k0 + s_src[r] * 8);
      }
#pragma unroll
      for (int r = 0; r < 4; ++r) {
        int s = tid + r * 256;
        gload_lds16(&lA[s * 8],
                    hsb + (size_t)(m0 + s_row[r]) * D_DIM + k0 + s_src[r] * 8);
      }
      __syncthreads();
#pragma unroll
      for (int kf = 0; kf < 2; ++kf) {
        short8 af[4], bfr[4];
        int cgrp = kf * 4 + lg;
#pragma unroll
        for (int mi = 0; mi < 4; ++mi) {
          int row = wr * 64 + mi * 16 + l15;
          af[mi] = *(const short8*)&lA[row * 64 + (cgrp ^ (row & 7)) * 8];
        }
#pragma unroll
        for (int ni = 0; ni < 4; ++ni) {
          int row = wc * 64 + ni * 16 + l15;
          bfr[ni] = *(const short8*)&lB[row * 64 + (cgrp ^ (row & 7)) * 8];
        }
#pragma unroll
        for (int mi = 0; mi < 4; ++mi)
#pragma unroll
          for (int ni = 0; ni < 4; ++ni)
            acc[mi][ni] = __builtin_amdgcn_mfma_f32_16x16x32_bf16(
                af[mi], bfr[ni], acc[mi][ni], 0, 0, 0);
      }
      __syncthreads();
    }
#pragma unroll
    for (int ni = 0; ni < 4; ++ni) {
      int h = n0 + wc * 64 + ni * 16 + l15;
      float ch = cvec[b * H_DIM + h];
      float wh = We_w[h];
#pragma unroll
      for (int mi = 0; mi < 4; ++mi)
#pragma unroll
        for (int r2 = 0; r2 < 4; ++r2)
          rowsum[mi][r2] += tanh_fast(acc[mi][ni][r2] + ch) * wh;
    }
  }
#pragma unroll
  for (int mi = 0; mi < 4; ++mi)
#pragma unroll
    for (int r2 = 0; r2 < 4; ++r2) {
      float v = rowsum[mi][r2];
      v += __shfl_xor(v, 1);
      v += __shfl_xor(v, 2);
      v += __shfl_xor(v, 4);
      v += __shfl_xor(v, 8);
      rowsum[mi][r2] = v;
    }
  if (l15 == 0) {
#pragma unroll
    for (int mi = 0; mi < 4; ++mi)
#pragma unroll
      for (int r2 = 0; r2 < 4; ++r2)
        scorebuf[wc][wr * 64 + mi * 16 + lg * 4 + r2] = rowsum[mi][r2];
  }
  __syncthreads();
  if (tid < 128) {
    score_part[(size_t)gy * M_TOT + m0 + tid] =
        scorebuf[0][tid] + scorebuf[1][tid];
  }
}

// ---------- kernel 3 (fallback path): in-kernel fp32->bf16 A staging ----------
__global__ __launch_bounds__(256) void score_gemm_fp32_kernel(
    const float* __restrict__ hs,
    const unsigned short* __restrict__ Wsb,
    const float* __restrict__ cvec,
    const float* __restrict__ We_w,
    float* __restrict__ score_part) {
  __shared__ __align__(16) unsigned short lA[128 * 64];
  __shared__ __align__(16) unsigned short lB[128 * 64];
  __shared__ float scorebuf[2][128];

  const int tid = threadIdx.x;
  const int lane = tid & 63;
  const int wave = tid >> 6;
  const int wr = wave >> 1;
  const int wc = wave & 1;
  const int mtile = blockIdx.x;
  const int gy = blockIdx.y;
  const int m0 = mtile * 128;
  const int b = mtile >> 5;

  const int l15 = lane & 15;
  const int lg = lane >> 4;

  float rowsum[4][4];
#pragma unroll
  for (int i = 0; i < 4; ++i)
#pragma unroll
    for (int j = 0; j < 4; ++j) rowsum[i][j] = 0.f;

  for (int nc = gy * 4; nc < gy * 4 + 4; ++nc) {
    const int n0 = nc * 128;
    f32x4 acc[4][4];
#pragma unroll
    for (int i = 0; i < 4; ++i)
#pragma unroll
      for (int j = 0; j < 4; ++j) acc[i][j] = (f32x4){0.f, 0.f, 0.f, 0.f};

    for (int k0 = 0; k0 < D_DIM; k0 += 64) {
#pragma unroll
      for (int r = 0; r < 4; ++r) {
        int s = tid + r * 256;
        int row = s >> 3, sl = s & 7;
        int src = sl ^ (row & 7);
        gload_lds16(&lB[s * 8], Wsb + (size_t)(n0 + row) * D_DIM + k0 + src * 8);
      }
      float4 a0[4], a1[4];
#pragma unroll
      for (int r = 0; r < 4; ++r) {
        int s = tid + r * 256;
        int row = s >> 3, sl = s & 7;
        int src = sl ^ (row & 7);
        const float* ga = hs + (size_t)(m0 + row) * D_DIM + k0 + src * 8;
        a0[r] = *(const float4*)ga;
        a1[r] = *(const float4*)(ga + 4);
      }
#pragma unroll
      for (int r = 0; r < 4; ++r) {
        int s = tid + r * 256;
        union { unsigned short us[8]; short8 v; } pk;
        pk.us[0] = f2bf(a0[r].x); pk.us[1] = f2bf(a0[r].y);
        pk.us[2] = f2bf(a0[r].z); pk.us[3] = f2bf(a0[r].w);
        pk.us[4] = f2bf(a1[r].x); pk.us[5] = f2bf(a1[r].y);
        pk.us[6] = f2bf(a1[r].z); pk.us[7] = f2bf(a1[r].w);
        *(short8*)(&lA[s * 8]) = pk.v;
      }
      __syncthreads();
#pragma unroll
      for (int kf = 0; kf < 2; ++kf) {
        short8 af[4], bfr[4];
        int cgrp = kf * 4 + lg;
#pragma unroll
        for (int mi = 0; mi < 4; ++mi) {
          int row = wr * 64 + mi * 16 + l15;
          af[mi] = *(const short8*)&lA[row * 64 + (cgrp ^ (row & 7)) * 8];
        }
#pragma unroll
        for (int ni = 0; ni < 4; ++ni) {
          int row = wc * 64 + ni * 16 + l15;
          bfr[ni] = *(const short8*)&lB[row * 64 + (cgrp ^ (row & 7)) * 8];
        }
#pragma unroll
        for (int mi = 0; mi < 4; ++mi)
#pragma unroll
          for (int ni = 0; ni < 4; ++ni)
            acc[mi][ni] = __builtin_amdgcn_mfma_f32_16x16x32_bf16(
                af[mi], bfr[ni], acc[mi][ni], 0, 0, 0);
      }
      __syncthreads();
    }
#pragma unroll
    for (int ni = 0; ni < 4; ++ni) {
      int h = n0 + wc * 64 + ni * 16 + l15;
      float ch = cvec[b * H_DIM + h];
      float wh = We_w[h];
#pragma unroll
      for (int mi = 0; mi < 4; ++mi)
#pragma unroll
        for (int r2 = 0; r2 < 4; ++r2)
          rowsum[mi][r2] += tanh_fast(acc[mi][ni][r2] + ch) * wh;
    }
  }
#pragma unroll
  for (int mi = 0; mi < 4; ++mi)
#pragma unroll
    for (int r2 = 0; r2 < 4; ++r2) {
      float v = rowsum[mi][r2];
      v += __shfl_xor(v, 1);
      v += __shfl_xor(v, 2);
      v += __shfl_xor(v, 4);
      v += __shfl_xor(v, 8);
      rowsum[mi][r2] = v;
    }
  if (l15 == 0) {
#pragma unroll
    for (int mi = 0; mi < 4; ++mi)
#pragma unroll
      for (int r2 = 0; r2 < 4; ++r2)
        scorebuf[wc][wr * 64 + mi * 16 + lg * 4 + r2] = rowsum[mi][r2];
  }
  __syncthreads();
  if (tid < 128) {
    score_part[(size_t)gy * M_TOT + m0 + tid] =
        scorebuf[0][tid] + scorebuf[1][tid];
  }
}

// ---------- kernel 4: softmax over S with rel-position bias ----------
__global__ void softmax_kernel(const float* __restrict__ part,
                               const int* __restrict__ hs_i,
                               const int* __restrict__ ht_i,
                               const float* __restrict__ emb,
                               const float* __restrict__ lam,
                               float* __restrict__ wout) {
  int b = blockIdx.x;
  int tid = threadIdx.x;
  float lam0 = lam[0], lam1 = lam[1], lam2 = lam[2];
  int tk = ht_i[b];
  float xs[16];
  float mx = -1e30f;
#pragma unroll
  for (int i = 0; i < 16; ++i) {
    int s = tid + i * 256;
    size_t m = (size_t)b * S_LEN + s;
    float x = part[m] + part[M_TOT + m];
    int idx = hs_i[m] * 512 + tk;
    const float* e = emb + (size_t)idx * 3;
    x += e[0] * lam0 + e[1] * lam1 + e[2] * lam2;
    xs[i] = x;
    mx = fmaxf(mx, x);
  }
  __shared__ float redm[4];
  __shared__ float reds[4];
#pragma unroll
  for (int off = 32; off >= 1; off >>= 1) mx = fmaxf(mx, __shfl_xor(mx, off));
  if ((tid & 63) == 0) redm[tid >> 6] = mx;
  __syncthreads();
  mx = fmaxf(fmaxf(redm[0], redm[1]), fmaxf(redm[2], redm[3]));
  float sum = 0.f;
#pragma unroll
  for (int i = 0; i < 16; ++i) {
    xs[i] = __expf(xs[i] - mx);
    sum += xs[i];
  }
#pragma unroll
  for (int off = 32; off >= 1; off >>= 1) sum += __shfl_xor(sum, off);
  if ((tid & 63) == 0) reds[tid >> 6] = sum;
  __syncthreads();
  sum = reds[0] + reds[1] + reds[2] + reds[3];
  float inv = 1.0f / sum;
#pragma unroll
  for (int i = 0; i < 16; ++i)
    wout[(size_t)b * S_LEN + tid + i * 256] = xs[i] * inv;
}

// ---------- kernel 5: u[b,d] = sum_s w[b,s]*hs[b,s,d] ----------
__global__ void wsum_kernel(const float* __restrict__ hs,
                            const float* __restrict__ w,
                            float* __restrict__ u) {
  int bx = blockIdx.x;
  int b = bx >> 5;
  int sc = bx & 31;
  int tid = threadIdx.x;
  int d = tid * 4;
  int s0 = sc * 128;
  const float* base = hs + ((size_t)b * S_LEN + s0) * D_DIM + d;
  const float* wrow = w + (size_t)b * S_LEN + s0;
  float4 acc = {0.f, 0.f, 0.f, 0.f};
#pragma unroll 4
  for (int i = 0; i < 128; ++i) {
    float ww = wrow[i];
    float4 v = *(const float4*)(base + (size_t)i * D_DIM);
    acc.x += ww * v.x;
    acc.y += ww * v.y;
    acc.z += ww * v.z;
    acc.w += ww * v.w;
  }
  atomicAdd(&u[b * D_DIM + d + 0], acc.x);
  atomicAdd(&u[b * D_DIM + d + 1], acc.y);
  atomicAdd(&u[b * D_DIM + d + 2], acc.z);
  atomicAdd(&u[b * D_DIM + d + 3], acc.w);
}

// ---------- kernel 6: alpha[b,h] = u[b]·Ws_w[h] + Ws_b[h] ----------
__global__ void alpha_kernel(const float* __restrict__ u,
                             const float* __restrict__ Ws_w,
                             const float* __restrict__ Ws_b,
                             float* __restrict__ out) {
  int gw = blockIdx.x * 4 + (threadIdx.x >> 6);
  int lane = threadIdx.x & 63;
  int b = gw >> 10;
  int h = gw & 1023;
  const float* ur = u + b * D_DIM;
  const float* wrow = Ws_w + (size_t)h * D_DIM;
  float acc = 0.f;
#pragma unroll
  for (int i = 0; i < 4; ++i) {
    int d = lane * 4 + i * 256;
    float4 x = *(const float4*)(ur + d);
    float4 y = *(const float4*)(wrow + d);
    acc += x.x * y.x + x.y * y.y + x.z * y.z + x.w * y.w;
  }
#pragma unroll
  for (int off = 32; off >= 1; off >>= 1) acc += __shfl_xor(acc, off);
  if (lane == 0) out[b * H_DIM + h] = acc + Ws_b[h];
}

extern "C" void kernel_launch(void* const* d_in, const int* in_sizes, int n_in,
                              void* d_out, int out_size, void* d_ws,
                              size_t ws_size, hipStream_t stream) {
  const float* hs = (const float*)d_in[0];
  const float* ht_k = (const float*)d_in[1];
  const float* hm_k = (const float*)d_in[2];
  const float* Ws_w = (const float*)d_in[3];
  const float* Ws_b = (const float*)d_in[4];
  const float* Wt_w = (const float*)d_in[5];
  const float* Wt_b = (const float*)d_in[6];
  const float* Wr_w = (const float*)d_in[7];
  const float* Wr_b = (const float*)d_in[8];
  const float* We_w = (const float*)d_in[9];
  const float* emb = (const float*)d_in[11];
  const float* lam = (const float*)d_in[12];
  const int* hs_i = (const int*)d_in[13];
  const int* ht_i = (const int*)d_in[14];
  float* out = (float*)d_out;

  const size_t HSB_BYTES = (size_t)M_TOT * D_DIM * 2;  // 128 MB
  const size_t FAST_NEEDED = HSB_BYTES + 2097152 + 524288 + 262144 + 65536;

  char* ws = (char*)d_ws;
  if (ws_size >= FAST_NEEDED) {
    unsigned short* hsb = (unsigned short*)ws;
    unsigned short* Wsb = (unsigned short*)(ws + HSB_BYTES);
    float* part = (float*)(ws + HSB_BYTES + 2097152);
    float* wgt = (float*)(ws + HSB_BYTES + 2097152 + 524288);
    float* u = (float*)(ws + HSB_BYTES + 2097152 + 524288 + 262144);
    float* cvec = u + B_SZ * D_DIM;  // reuse tail? no — separate region below
    // place cvec in the part buffer's padding is unsafe; use dedicated space:
    // layout: [hsb 128M][Wsb 2M][part 512K][wgt 256K][u 64K][cvec 64K]
    cvec = (float*)(ws + HSB_BYTES + 2097152 + 524288 + 262144 + 65536 - 65536);
    // ^ need cvec distinct from u: extend layout
    cvec = (float*)(ws + HSB_BYTES + 2097152 + 524288 + 262144 + 65536);
    // (FAST_NEEDED above reserves through u; cvec adds 64 KB more, checked:)
    if (ws_size >= FAST_NEEDED + 65536) {
      cvt_hs_kernel<<<32768, 256, 0, stream>>>(hs, hsb);
      cvt_w_kernel<<<512, 256, 0, stream>>>(Ws_w, Wsb);
      prep_c_kernel<<<4096, 256, 0, stream>>>(ht_k, hm_k, Wt_w, Wt_b, Wr_w,
                                              Wr_b, cvec);
      dim3 g2(512, 2);
      score_gemm_kernel<<<g2, 256, 0, stream>>>(hsb, Wsb, cvec, We_w, part);
      softmax_kernel<<<16, 256, 0, stream>>>(part, hs_i, ht_i, emb, lam, wgt);
      hipMemsetAsync(u, 0, B_SZ * D_DIM * sizeof(float), stream);
      wsum_kernel<<<512, 256, 0, stream>>>(hs, wgt, u);
      alpha_kernel<<<4096, 256, 0, stream>>>(u, Ws_w, Ws_b, out);
      return;
    }
  }

  // fallback: small-ws path (round-1 structure)
  unsigned short* Wsb = (unsigned short*)(ws);
  float* cvec = (float*)(ws + 2097152);
  float* part = (float*)(ws + 2097152 + 65536);
  float* wgt = (float*)(ws + 2097152 + 65536 + 524288);
  float* u = (float*)(ws + 2097152 + 65536 + 524288 + 262144);

  cvt_w_kernel<<<512, 256, 0, stream>>>(Ws_w, Wsb);
  prep_c_kernel<<<4096, 256, 0, stream>>>(ht_k, hm_k, Wt_w, Wt_b, Wr_w, Wr_b,
                                          cvec);
  dim3 g2(512, 2);
  score_gemm_fp32_kernel<<<g2, 256, 0, stream>>>(hs, Wsb, cvec, We_w, part);
  softmax_kernel<<<16, 256, 0, stream>>>(part, hs_i, ht_i, emb, lam, wgt);
  hipMemsetAsync(u, 0, B_SZ * D_DIM * sizeof(float), stream);
  wsum_kernel<<<512, 256, 0, stream>>>(hs, wgt, u);
  alpha_kernel<<<4096, 256, 0, stream>>>(u, Ws_w, Ws_b, out);
}

// Round 3
// 303.180 us; speedup vs baseline: 1.3209x; 1.1401x over previous
//
#include <hip/hip_runtime.h>
#include <hip/hip_bf16.h>
#include <cstdint>
#include <cstddef>

typedef __attribute__((ext_vector_type(4))) float f32x4;
typedef __attribute__((ext_vector_type(8))) short short8;

#define S_LEN 4096
#define D_DIM 1024
#define H_DIM 1024
#define B_SZ  16
#define M_TOT (B_SZ * S_LEN)  // 65536
#define NT 32                 // K tiles of 32

// ---------- helpers ----------
__device__ __forceinline__ unsigned short f2bf(float f) {
  unsigned int u = __float_as_uint(f);
  u += 0x7fffu + ((u >> 16) & 1u);
  return (unsigned short)(u >> 16);
}

__device__ __forceinline__ void gload_lds16(void* lds, const void* g) {
  __builtin_amdgcn_global_load_lds(
      (const __attribute__((address_space(1))) unsigned int*)g,
      (__attribute__((address_space(3))) unsigned int*)lds, 16, 0, 0);
}

__device__ __forceinline__ float tanh_fast(float x) {
  return 1.0f - 2.0f / (1.0f + __expf(2.0f * x));
}

// ---------- kernel 0: hs fp32 -> bf16 ----------
__global__ void cvt_hs_kernel(const float* __restrict__ w,
                              unsigned short* __restrict__ o) {
  size_t i = ((size_t)blockIdx.x * 256 + threadIdx.x) * 8;
  float4 v0 = *(const float4*)(w + i);
  float4 v1 = *(const float4*)(w + i + 4);
  union { unsigned short us[8]; short8 v; } pk;
  pk.us[0] = f2bf(v0.x); pk.us[1] = f2bf(v0.y);
  pk.us[2] = f2bf(v0.z); pk.us[3] = f2bf(v0.w);
  pk.us[4] = f2bf(v1.x); pk.us[5] = f2bf(v1.y);
  pk.us[6] = f2bf(v1.z); pk.us[7] = f2bf(v1.w);
  *(short8*)(o + i) = pk.v;
}

// ---------- kernel 1: Ws_w fp32 -> bf16 ----------
__global__ void cvt_w_kernel(const float* __restrict__ w,
                             unsigned short* __restrict__ o) {
  int i = (blockIdx.x * 256 + threadIdx.x) * 8;
  float4 v0 = *(const float4*)(w + i);
  float4 v1 = *(const float4*)(w + i + 4);
  union { unsigned short us[8]; short8 v; } pk;
  pk.us[0] = f2bf(v0.x); pk.us[1] = f2bf(v0.y);
  pk.us[2] = f2bf(v0.z); pk.us[3] = f2bf(v0.w);
  pk.us[4] = f2bf(v1.x); pk.us[5] = f2bf(v1.y);
  pk.us[6] = f2bf(v1.z); pk.us[7] = f2bf(v1.w);
  *(short8*)(o + i) = pk.v;
}

// ---------- kernel 2: c[b,h] ----------
__global__ void prep_c_kernel(const float* __restrict__ ht,
                              const float* __restrict__ hm,
                              const float* __restrict__ Wt_w,
                              const float* __restrict__ Wt_b,
                              const float* __restrict__ Wr_w,
                              const float* __restrict__ Wr_b,
                              float* __restrict__ cvec) {
  int gw = blockIdx.x * 4 + (threadIdx.x >> 6);
  int lane = threadIdx.x & 63;
  int b = gw >> 10;
  int h = gw & 1023;
  const float* a1 = ht + b * D_DIM;
  const float* w1 = Wt_w + (size_t)h * D_DIM;
  const float* a2 = hm + b * H_DIM;
  const float* w2 = Wr_w + (size_t)h * H_DIM;
  float acc = 0.f;
#pragma unroll
  for (int i = 0; i < 4; ++i) {
    int d = lane * 4 + i * 256;
    float4 x1 = *(const float4*)(a1 + d);
    float4 y1 = *(const float4*)(w1 + d);
    float4 x2 = *(const float4*)(a2 + d);
    float4 y2 = *(const float4*)(w2 + d);
    acc += x1.x * y1.x + x1.y * y1.y + x1.z * y1.z + x1.w * y1.w;
    acc += x2.x * y2.x + x2.y * y2.y + x2.z * y2.z + x2.w * y2.w;
  }
#pragma unroll
  for (int off = 32; off >= 1; off >>= 1) acc += __shfl_xor(acc, off);
  if (lane == 0) cvec[b * H_DIM + h] = acc + Wt_b[h] + Wr_b[h];
}

// ---------- 256x256 pipelined fused GEMM ----------
// Quad-buffered LDS, prefetch distance 3, counted vmcnt(8) per K-tile.
// LDS layout per buffer: [256 rows][32 k] bf16, row = 64 B = 4 slots of 16 B,
// slot swizzle: phys_slot = log_slot ^ ((row>>1)&3)  (applied to BOTH the
// global source address at stage time and the ds_read address — m201 rule).
__device__ __forceinline__ void issue_tile(int kt, int tid,
                                           unsigned short* lA,
                                           unsigned short* lB,
                                           const unsigned short* pA0,
                                           const unsigned short* pA1,
                                           const unsigned short* pB0,
                                           const unsigned short* pB1) {
  int bq = (kt & 3) * 8192;
  size_t ko = (size_t)kt * 32;
  gload_lds16(&lA[bq + tid * 8], pA0 + ko);
  gload_lds16(&lA[bq + 4096 + tid * 8], pA1 + ko);
  gload_lds16(&lB[bq + tid * 8], pB0 + ko);
  gload_lds16(&lB[bq + 4096 + tid * 8], pB1 + ko);
}

__device__ __forceinline__ void compute_tile(const unsigned short* bufA,
                                             const unsigned short* bufB,
                                             const int* aoff, const int* boff,
                                             f32x4 (&acc)[8][4]) {
  short8 bfr[4];
#pragma unroll
  for (int ni = 0; ni < 4; ++ni)
    bfr[ni] = *(const short8*)(bufB + boff[ni]);
  short8 af[4];
#pragma unroll
  for (int mi = 0; mi < 4; ++mi)
    af[mi] = *(const short8*)(bufA + aoff[mi]);
  __builtin_amdgcn_s_setprio(1);
#pragma unroll
  for (int mi = 0; mi < 4; ++mi)
#pragma unroll
    for (int ni = 0; ni < 4; ++ni)
      acc[mi][ni] = __builtin_amdgcn_mfma_f32_16x16x32_bf16(
          af[mi], bfr[ni], acc[mi][ni], 0, 0, 0);
  __builtin_amdgcn_s_setprio(0);
#pragma unroll
  for (int mi = 0; mi < 4; ++mi)
    af[mi] = *(const short8*)(bufA + aoff[4 + mi]);
  __builtin_amdgcn_s_setprio(1);
#pragma unroll
  for (int mi = 0; mi < 4; ++mi)
#pragma unroll
    for (int ni = 0; ni < 4; ++ni)
      acc[4 + mi][ni] = __builtin_amdgcn_mfma_f32_16x16x32_bf16(
          af[mi], bfr[ni], acc[4 + mi][ni], 0, 0, 0);
  __builtin_amdgcn_s_setprio(0);
}

__global__ __launch_bounds__(512, 2) void score_gemm2_kernel(
    const unsigned short* __restrict__ hsb,
    const unsigned short* __restrict__ Wsb,
    const float* __restrict__ cvec,
    const float* __restrict__ We_w,
    float* __restrict__ score_part) {
  extern __shared__ unsigned short dynls[];  // 4*16KB A + 4*16KB B = 128 KiB
  unsigned short* lA = dynls;
  unsigned short* lB = dynls + 4 * 8192;
  __shared__ float scorebuf[4][256];

  const int tid = threadIdx.x;
  const int lane = tid & 63;
  const int wave = tid >> 6;
  const int wm = wave >> 2;  // 0..1 row half (128 rows each)
  const int wn = wave & 3;   // 0..3 col slice (64 cols each)
  const int l15 = lane & 15;
  const int lg = lane >> 4;

  // XCD-chunked dispatch swizzle: keep an mtile's 4 nc-siblings on one XCD
  int d = blockIdx.x;                    // 0..1023
  int tileid = (d & 7) * 128 + (d >> 3); // bijective (1024 % 8 == 0)
  const int mtile = tileid >> 2;
  const int nc = tileid & 3;
  const int m0 = mtile * 256;
  const int n0 = nc * 256;
  const int b = m0 >> 12;  // batch = m0 / 4096

  // staging: per thread, two 16B rounds per operand per K-tile
  const int r0 = tid >> 2;        // rows 0..127
  const int r1 = 128 + r0;        // rows 128..255
  const int sp = tid & 3;         // phys slot
  const int c0 = (sp ^ ((r0 >> 1) & 3)) * 8;  // pre-swizzled source col
  const int c1 = (sp ^ ((r1 >> 1) & 3)) * 8;
  const unsigned short* pA0 = hsb + (size_t)(m0 + r0) * D_DIM + c0;
  const unsigned short* pA1 = hsb + (size_t)(m0 + r1) * D_DIM + c1;
  const unsigned short* pB0 = Wsb + (size_t)(n0 + r0) * D_DIM + c0;
  const unsigned short* pB1 = Wsb + (size_t)(n0 + r1) * D_DIM + c1;

  // fragment read offsets (elements), swizzled
  int aoff[8], boff[4];
#pragma unroll
  for (int mi = 0; mi < 8; ++mi) {
    int row = wm * 128 + mi * 16 + l15;
    aoff[mi] = row * 32 + (lg ^ ((row >> 1) & 3)) * 8;
  }
#pragma unroll
  for (int ni = 0; ni < 4; ++ni) {
    int row = wn * 64 + ni * 16 + l15;
    boff[ni] = row * 32 + (lg ^ ((row >> 1) & 3)) * 8;
  }

  f32x4 acc[8][4];
#pragma unroll
  for (int i = 0; i < 8; ++i)
#pragma unroll
    for (int j = 0; j < 4; ++j) acc[i][j] = (f32x4){0.f, 0.f, 0.f, 0.f};

  // prologue: fill pipeline 3 deep
  issue_tile(0, tid, lA, lB, pA0, pA1, pB0, pB1);
  issue_tile(1, tid, lA, lB, pA0, pA1, pB0, pB1);
  issue_tile(2, tid, lA, lB, pA0, pA1, pB0, pB1);
  asm volatile("s_waitcnt vmcnt(8)\n\ts_barrier" ::: "memory");

  for (int kt = 0; kt < NT - 3; ++kt) {
    issue_tile(kt + 3, tid, lA, lB, pA0, pA1, pB0, pB1);
    int bq = (kt & 3) * 8192;
    compute_tile(lA + bq, lB + bq, aoff, boff, acc);
    asm volatile("s_waitcnt vmcnt(8)\n\ts_barrier" ::: "memory");
  }
  {
    int bq = ((NT - 3) & 3) * 8192;
    compute_tile(lA + bq, lB + bq, aoff, boff, acc);
    asm volatile("s_waitcnt vmcnt(4)\n\ts_barrier" ::: "memory");
  }
  {
    int bq = ((NT - 2) & 3) * 8192;
    compute_tile(lA + bq, lB + bq, aoff, boff, acc);
    asm volatile("s_waitcnt vmcnt(0)\n\ts_barrier" ::: "memory");
  }
  {
    int bq = ((NT - 1) & 3) * 8192;
    compute_tile(lA + bq, lB + bq, aoff, boff, acc);
  }

  // epilogue: tanh(acc + c)*We, reduce over this block's 256 columns
  float chv[4], whv[4];
#pragma unroll
  for (int ni = 0; ni < 4; ++ni) {
    int h = n0 + wn * 64 + ni * 16 + l15;
    chv[ni] = cvec[b * H_DIM + h];
    whv[ni] = We_w[h];
  }
#pragma unroll
  for (int mi = 0; mi < 8; ++mi)
#pragma unroll
    for (int r = 0; r < 4; ++r) {
      float s = 0.f;
#pragma unroll
      for (int ni = 0; ni < 4; ++ni)
        s += tanh_fast(acc[mi][ni][r] + chv[ni]) * whv[ni];
      s += __shfl_xor(s, 1);
      s += __shfl_xor(s, 2);
      s += __shfl_xor(s, 4);
      s += __shfl_xor(s, 8);
      if (l15 == 0) scorebuf[wn][wm * 128 + mi * 16 + lg * 4 + r] = s;
    }
  __syncthreads();
  if (tid < 256) {
    float s = scorebuf[0][tid] + scorebuf[1][tid] + scorebuf[2][tid] +
              scorebuf[3][tid];
    score_part[(size_t)nc * M_TOT + m0 + tid] = s;
  }
}

// ---------- fallback GEMM (round-1 structure, fp32 A in-kernel cvt) ----------
__global__ __launch_bounds__(256) void score_gemm_fp32_kernel(
    const float* __restrict__ hs,
    const unsigned short* __restrict__ Wsb,
    const float* __restrict__ cvec,
    const float* __restrict__ We_w,
    float* __restrict__ score_part) {
  __shared__ __align__(16) unsigned short lA[128 * 64];
  __shared__ __align__(16) unsigned short lB[128 * 64];
  __shared__ float scorebuf[2][128];

  const int tid = threadIdx.x;
  const int lane = tid & 63;
  const int wave = tid >> 6;
  const int wr = wave >> 1;
  const int wc = wave & 1;
  const int mtile = blockIdx.x;
  const int gy = blockIdx.y;
  const int m0 = mtile * 128;
  const int b = mtile >> 5;
  const int l15 = lane & 15;
  const int lg = lane >> 4;

  float rowsum[4][4];
#pragma unroll
  for (int i = 0; i < 4; ++i)
#pragma unroll
    for (int j = 0; j < 4; ++j) rowsum[i][j] = 0.f;

  for (int ncq = gy * 4; ncq < gy * 4 + 4; ++ncq) {
    const int n0 = ncq * 128;
    f32x4 acc[4][4];
#pragma unroll
    for (int i = 0; i < 4; ++i)
#pragma unroll
      for (int j = 0; j < 4; ++j) acc[i][j] = (f32x4){0.f, 0.f, 0.f, 0.f};

    for (int k0 = 0; k0 < D_DIM; k0 += 64) {
#pragma unroll
      for (int r = 0; r < 4; ++r) {
        int s = tid + r * 256;
        int row = s >> 3, sl = s & 7;
        int src = sl ^ (row & 7);
        gload_lds16(&lB[s * 8], Wsb + (size_t)(n0 + row) * D_DIM + k0 + src * 8);
      }
      float4 a0[4], a1[4];
#pragma unroll
      for (int r = 0; r < 4; ++r) {
        int s = tid + r * 256;
        int row = s >> 3, sl = s & 7;
        int src = sl ^ (row & 7);
        const float* ga = hs + (size_t)(m0 + row) * D_DIM + k0 + src * 8;
        a0[r] = *(const float4*)ga;
        a1[r] = *(const float4*)(ga + 4);
      }
#pragma unroll
      for (int r = 0; r < 4; ++r) {
        int s = tid + r * 256;
        union { unsigned short us[8]; short8 v; } pk;
        pk.us[0] = f2bf(a0[r].x); pk.us[1] = f2bf(a0[r].y);
        pk.us[2] = f2bf(a0[r].z); pk.us[3] = f2bf(a0[r].w);
        pk.us[4] = f2bf(a1[r].x); pk.us[5] = f2bf(a1[r].y);
        pk.us[6] = f2bf(a1[r].z); pk.us[7] = f2bf(a1[r].w);
        *(short8*)(&lA[s * 8]) = pk.v;
      }
      __syncthreads();
#pragma unroll
      for (int kf = 0; kf < 2; ++kf) {
        short8 af[4], bfr[4];
        int cgrp = kf * 4 + lg;
#pragma unroll
        for (int mi = 0; mi < 4; ++mi) {
          int row = wr * 64 + mi * 16 + l15;
          af[mi] = *(const short8*)&lA[row * 64 + (cgrp ^ (row & 7)) * 8];
        }
#pragma unroll
        for (int ni = 0; ni < 4; ++ni) {
          int row = wc * 64 + ni * 16 + l15;
          bfr[ni] = *(const short8*)&lB[row * 64 + (cgrp ^ (row & 7)) * 8];
        }
#pragma unroll
        for (int mi = 0; mi < 4; ++mi)
#pragma unroll
          for (int ni = 0; ni < 4; ++ni)
            acc[mi][ni] = __builtin_amdgcn_mfma_f32_16x16x32_bf16(
                af[mi], bfr[ni], acc[mi][ni], 0, 0, 0);
      }
      __syncthreads();
    }
#pragma unroll
    for (int ni = 0; ni < 4; ++ni) {
      int h = n0 + wc * 64 + ni * 16 + l15;
      float ch = cvec[b * H_DIM + h];
      float wh = We_w[h];
#pragma unroll
      for (int mi = 0; mi < 4; ++mi)
#pragma unroll
        for (int r2 = 0; r2 < 4; ++r2)
          rowsum[mi][r2] += tanh_fast(acc[mi][ni][r2] + ch) * wh;
    }
  }
#pragma unroll
  for (int mi = 0; mi < 4; ++mi)
#pragma unroll
    for (int r2 = 0; r2 < 4; ++r2) {
      float v = rowsum[mi][r2];
      v += __shfl_xor(v, 1);
      v += __shfl_xor(v, 2);
      v += __shfl_xor(v, 4);
      v += __shfl_xor(v, 8);
      rowsum[mi][r2] = v;
    }
  if (l15 == 0) {
#pragma unroll
    for (int mi = 0; mi < 4; ++mi)
#pragma unroll
      for (int r2 = 0; r2 < 4; ++r2)
        scorebuf[wc][wr * 64 + mi * 16 + lg * 4 + r2] = rowsum[mi][r2];
  }
  __syncthreads();
  if (tid < 128) {
    score_part[(size_t)gy * M_TOT + m0 + tid] =
        scorebuf[0][tid] + scorebuf[1][tid];
  }
}

// ---------- softmax over S with rel-position bias ----------
__global__ void softmax_kernel(const float* __restrict__ part,
                               const int* __restrict__ hs_i,
                               const int* __restrict__ ht_i,
                               const float* __restrict__ emb,
                               const float* __restrict__ lam,
                               float* __restrict__ wout, int nparts) {
  int b = blockIdx.x;
  int tid = threadIdx.x;
  float lam0 = lam[0], lam1 = lam[1], lam2 = lam[2];
  int tk = ht_i[b];
  float xs[16];
  float mx = -1e30f;
#pragma unroll
  for (int i = 0; i < 16; ++i) {
    int s = tid + i * 256;
    size_t m = (size_t)b * S_LEN + s;
    float x = 0.f;
    for (int g = 0; g < nparts; ++g) x += part[(size_t)g * M_TOT + m];
    int idx = hs_i[m] * 512 + tk;
    const float* e = emb + (size_t)idx * 3;
    x += e[0] * lam0 + e[1] * lam1 + e[2] * lam2;
    xs[i] = x;
    mx = fmaxf(mx, x);
  }
  __shared__ float redm[4];
  __shared__ float reds[4];
#pragma unroll
  for (int off = 32; off >= 1; off >>= 1) mx = fmaxf(mx, __shfl_xor(mx, off));
  if ((tid & 63) == 0) redm[tid >> 6] = mx;
  __syncthreads();
  mx = fmaxf(fmaxf(redm[0], redm[1]), fmaxf(redm[2], redm[3]));
  float sum = 0.f;
#pragma unroll
  for (int i = 0; i < 16; ++i) {
    xs[i] = __expf(xs[i] - mx);
    sum += xs[i];
  }
#pragma unroll
  for (int off = 32; off >= 1; off >>= 1) sum += __shfl_xor(sum, off);
  if ((tid & 63) == 0) reds[tid >> 6] = sum;
  __syncthreads();
  sum = reds[0] + reds[1] + reds[2] + reds[3];
  float inv = 1.0f / sum;
#pragma unroll
  for (int i = 0; i < 16; ++i)
    wout[(size_t)b * S_LEN + tid + i * 256] = xs[i] * inv;
}

// ---------- wsum (bf16 input): u[b,d] = sum_s w[b,s]*hsb[b,s,d] ----------
__global__ void wsum_bf16_kernel(const unsigned short* __restrict__ hsb,
                                 const float* __restrict__ w,
                                 float* __restrict__ u) {
  int bx = blockIdx.x;
  int b = bx >> 5;
  int sc = bx & 31;
  int tid = threadIdx.x;
  int dcol = tid * 4;
  int s0 = sc * 128;
  const unsigned short* base = hsb + ((size_t)b * S_LEN + s0) * D_DIM + dcol;
  const float* wrow = w + (size_t)b * S_LEN + s0;
  float4 acc = {0.f, 0.f, 0.f, 0.f};
#pragma unroll 4
  for (int i = 0; i < 128; ++i) {
    float ww = wrow[i];
    ushort2 v01 = *(const ushort2*)(base + (size_t)i * D_DIM);
    ushort2 v23 = *(const ushort2*)(base + (size_t)i * D_DIM + 2);
    acc.x += ww * __uint_as_float((unsigned int)v01.x << 16);
    acc.y += ww * __uint_as_float((unsigned int)v01.y << 16);
    acc.z += ww * __uint_as_float((unsigned int)v23.x << 16);
    acc.w += ww * __uint_as_float((unsigned int)v23.y << 16);
  }
  atomicAdd(&u[b * D_DIM + dcol + 0], acc.x);
  atomicAdd(&u[b * D_DIM + dcol + 1], acc.y);
  atomicAdd(&u[b * D_DIM + dcol + 2], acc.z);
  atomicAdd(&u[b * D_DIM + dcol + 3], acc.w);
}

// ---------- wsum (fp32 fallback) ----------
__global__ void wsum_kernel(const float* __restrict__ hs,
                            const float* __restrict__ w,
                            float* __restrict__ u) {
  int bx = blockIdx.x;
  int b = bx >> 5;
  int sc = bx & 31;
  int tid = threadIdx.x;
  int dcol = tid * 4;
  int s0 = sc * 128;
  const float* base = hs + ((size_t)b * S_LEN + s0) * D_DIM + dcol;
  const float* wrow = w + (size_t)b * S_LEN + s0;
  float4 acc = {0.f, 0.f, 0.f, 0.f};
#pragma unroll 4
  for (int i = 0; i < 128; ++i) {
    float ww = wrow[i];
    float4 v = *(const float4*)(base + (size_t)i * D_DIM);
    acc.x += ww * v.x;
    acc.y += ww * v.y;
    acc.z += ww * v.z;
    acc.w += ww * v.w;
  }
  atomicAdd(&u[b * D_DIM + dcol + 0], acc.x);
  atomicAdd(&u[b * D_DIM + dcol + 1], acc.y);
  atomicAdd(&u[b * D_DIM + dcol + 2], acc.z);
  atomicAdd(&u[b * D_DIM + dcol + 3], acc.w);
}

// ---------- alpha[b,h] = u[b]·Ws_w[h] + Ws_b[h] ----------
__global__ void alpha_kernel(const float* __restrict__ u,
                             const float* __restrict__ Ws_w,
                             const float* __restrict__ Ws_b,
                             float* __restrict__ out) {
  int gw = blockIdx.x * 4 + (threadIdx.x >> 6);
  int lane = threadIdx.x & 63;
  int b = gw >> 10;
  int h = gw & 1023;
  const float* ur = u + b * D_DIM;
  const float* wrow = Ws_w + (size_t)h * D_DIM;
  float acc = 0.f;
#pragma unroll
  for (int i = 0; i < 4; ++i) {
    int dcol = lane * 4 + i * 256;
    float4 x = *(const float4*)(ur + dcol);
    float4 y = *(const float4*)(wrow + dcol);
    acc += x.x * y.x + x.y * y.y + x.z * y.z + x.w * y.w;
  }
#pragma unroll
  for (int off = 32; off >= 1; off >>= 1) acc += __shfl_xor(acc, off);
  if (lane == 0) out[b * H_DIM + h] = acc + Ws_b[h];
}

extern "C" void kernel_launch(void* const* d_in, const int* in_sizes, int n_in,
                              void* d_out, int out_size, void* d_ws,
                              size_t ws_size, hipStream_t stream) {
  const float* hs = (const float*)d_in[0];
  const float* ht_k = (const float*)d_in[1];
  const float* hm_k = (const float*)d_in[2];
  const float* Ws_w = (const float*)d_in[3];
  const float* Ws_b = (const float*)d_in[4];
  const float* Wt_w = (const float*)d_in[5];
  const float* Wt_b = (const float*)d_in[6];
  const float* Wr_w = (const float*)d_in[7];
  const float* Wr_b = (const float*)d_in[8];
  const float* We_w = (const float*)d_in[9];
  const float* emb = (const float*)d_in[11];
  const float* lam = (const float*)d_in[12];
  const int* hs_i = (const int*)d_in[13];
  const int* ht_i = (const int*)d_in[14];
  float* out = (float*)d_out;

  const size_t HSB = (size_t)M_TOT * D_DIM * 2;  // 128 MB
  // fast layout: [hsb][Wsb 2M][part 1M][wgt 256K][u 64K][cvec 64K]
  const size_t FAST_NEEDED = HSB + 2097152 + 1048576 + 262144 + 65536 + 65536;

  char* ws = (char*)d_ws;
  if (ws_size >= FAST_NEEDED) {
    unsigned short* hsb = (unsigned short*)ws;
    unsigned short* Wsb = (unsigned short*)(ws + HSB);
    float* part = (float*)(ws + HSB + 2097152);
    float* wgt = (float*)(ws + HSB + 2097152 + 1048576);
    float* u = (float*)(ws + HSB + 2097152 + 1048576 + 262144);
    float* cvec = (float*)(ws + HSB + 2097152 + 1048576 + 262144 + 65536);

    hipFuncSetAttribute((const void*)score_gemm2_kernel,
                        hipFuncAttributeMaxDynamicSharedMemorySize, 131072);

    cvt_hs_kernel<<<32768, 256, 0, stream>>>(hs, hsb);
    cvt_w_kernel<<<512, 256, 0, stream>>>(Ws_w, Wsb);
    prep_c_kernel<<<4096, 256, 0, stream>>>(ht_k, hm_k, Wt_w, Wt_b, Wr_w,
                                            Wr_b, cvec);
    score_gemm2_kernel<<<1024, 512, 131072, stream>>>(hsb, Wsb, cvec, We_w,
                                                      part);
    softmax_kernel<<<16, 256, 0, stream>>>(part, hs_i, ht_i, emb, lam, wgt, 4);
    hipMemsetAsync(u, 0, B_SZ * D_DIM * sizeof(float), stream);
    wsum_bf16_kernel<<<512, 256, 0, stream>>>(hsb, wgt, u);
    alpha_kernel<<<4096, 256, 0, stream>>>(u, Ws_w, Ws_b, out);
    return;
  }

  // fallback: small-ws path
  unsigned short* Wsb = (unsigned short*)(ws);
  float* cvec = (float*)(ws + 2097152);
  float* part = (float*)(ws + 2097152 + 65536);
  float* wgt = (float*)(ws + 2097152 + 65536 + 524288);
  float* u = (float*)(ws + 2097152 + 65536 + 524288 + 262144);

  cvt_w_kernel<<<512, 256, 0, stream>>>(Ws_w, Wsb);
  prep_c_kernel<<<4096, 256, 0, stream>>>(ht_k, hm_k, Wt_w, Wt_b, Wr_w, Wr_b,
                                          cvec);
  dim3 g2(512, 2);
  score_gemm_fp32_kernel<<<g2, 256, 0, stream>>>(hs, Wsb, cvec, We_w, part);
  softmax_kernel<<<16, 256, 0, stream>>>(part, hs_i, ht_i, emb, lam, wgt, 2);
  hipMemsetAsync(u, 0, B_SZ * D_DIM * sizeof(float), stream);
  wsum_kernel<<<512, 256, 0, stream>>>(hs, wgt, u);
  alpha_kernel<<<4096, 256, 0, stream>>>(u, Ws_w, Ws_b, out);
}

// Round 4
// 299.258 us; speedup vs baseline: 1.3383x; 1.0131x over previous
//
#include <hip/hip_runtime.h>
#include <hip/hip_bf16.h>
#include <cstdint>
#include <cstddef>

typedef __attribute__((ext_vector_type(4))) float f32x4;
typedef __attribute__((ext_vector_type(8))) short short8;

#define S_LEN 4096
#define D_DIM 1024
#define H_DIM 1024
#define B_SZ  16
#define M_TOT (B_SZ * S_LEN)  // 65536
#define NT 32                 // K tiles of 32

// ---------- helpers ----------
__device__ __forceinline__ unsigned short f2bf(float f) {
  unsigned int u = __float_as_uint(f);
  u += 0x7fffu + ((u >> 16) & 1u);
  return (unsigned short)(u >> 16);
}

__device__ __forceinline__ void gload_lds16(void* lds, const void* g) {
  __builtin_amdgcn_global_load_lds(
      (const __attribute__((address_space(1))) unsigned int*)g,
      (__attribute__((address_space(3))) unsigned int*)lds, 16, 0, 0);
}

__device__ __forceinline__ float tanh_fast(float x) {
  return 1.0f - 2.0f / (1.0f + __expf(2.0f * x));
}

#define WAITV(N) asm volatile("s_waitcnt vmcnt(" #N ")" ::: "memory")
#define BAR() __builtin_amdgcn_s_barrier()

// ---------- kernel 0: hs fp32 -> bf16 ----------
__global__ void cvt_hs_kernel(const float* __restrict__ w,
                              unsigned short* __restrict__ o) {
  size_t i = ((size_t)blockIdx.x * 256 + threadIdx.x) * 8;
  float4 v0 = *(const float4*)(w + i);
  float4 v1 = *(const float4*)(w + i + 4);
  union { unsigned short us[8]; short8 v; } pk;
  pk.us[0] = f2bf(v0.x); pk.us[1] = f2bf(v0.y);
  pk.us[2] = f2bf(v0.z); pk.us[3] = f2bf(v0.w);
  pk.us[4] = f2bf(v1.x); pk.us[5] = f2bf(v1.y);
  pk.us[6] = f2bf(v1.z); pk.us[7] = f2bf(v1.w);
  *(short8*)(o + i) = pk.v;
}

// ---------- kernel 1: Ws_w fp32 -> bf16 ----------
__global__ void cvt_w_kernel(const float* __restrict__ w,
                             unsigned short* __restrict__ o) {
  int i = (blockIdx.x * 256 + threadIdx.x) * 8;
  float4 v0 = *(const float4*)(w + i);
  float4 v1 = *(const float4*)(w + i + 4);
  union { unsigned short us[8]; short8 v; } pk;
  pk.us[0] = f2bf(v0.x); pk.us[1] = f2bf(v0.y);
  pk.us[2] = f2bf(v0.z); pk.us[3] = f2bf(v0.w);
  pk.us[4] = f2bf(v1.x); pk.us[5] = f2bf(v1.y);
  pk.us[6] = f2bf(v1.z); pk.us[7] = f2bf(v1.w);
  *(short8*)(o + i) = pk.v;
}

// ---------- kernel 2: c[b,h] ----------
__global__ void prep_c_kernel(const float* __restrict__ ht,
                              const float* __restrict__ hm,
                              const float* __restrict__ Wt_w,
                              const float* __restrict__ Wt_b,
                              const float* __restrict__ Wr_w,
                              const float* __restrict__ Wr_b,
                              float* __restrict__ cvec) {
  int gw = blockIdx.x * 4 + (threadIdx.x >> 6);
  int lane = threadIdx.x & 63;
  int b = gw >> 10;
  int h = gw & 1023;
  const float* a1 = ht + b * D_DIM;
  const float* w1 = Wt_w + (size_t)h * D_DIM;
  const float* a2 = hm + b * H_DIM;
  const float* w2 = Wr_w + (size_t)h * H_DIM;
  float acc = 0.f;
#pragma unroll
  for (int i = 0; i < 4; ++i) {
    int d = lane * 4 + i * 256;
    float4 x1 = *(const float4*)(a1 + d);
    float4 y1 = *(const float4*)(w1 + d);
    float4 x2 = *(const float4*)(a2 + d);
    float4 y2 = *(const float4*)(w2 + d);
    acc += x1.x * y1.x + x1.y * y1.y + x1.z * y1.z + x1.w * y1.w;
    acc += x2.x * y2.x + x2.y * y2.y + x2.z * y2.z + x2.w * y2.w;
  }
#pragma unroll
  for (int off = 32; off >= 1; off >>= 1) acc += __shfl_xor(acc, off);
  if (lane == 0) cvec[b * H_DIM + h] = acc + Wt_b[h] + Wr_b[h];
}

// ---------- 256x256 pipelined fused GEMM, frag-double-buffered ----------
__device__ __forceinline__ void issue_tile(int kt, int tid,
                                           unsigned short* lA,
                                           unsigned short* lB,
                                           const unsigned short* pA0,
                                           const unsigned short* pA1,
                                           const unsigned short* pB0,
                                           const unsigned short* pB1) {
  const int bq = (kt & 3) * 8192;
  const int ko = kt * 32;
  gload_lds16(&lA[bq + tid * 8], pA0 + ko);
  gload_lds16(&lA[bq + 4096 + tid * 8], pA1 + ko);
  gload_lds16(&lB[bq + tid * 8], pB0 + ko);
  gload_lds16(&lB[bq + 4096 + tid * 8], pB1 + ko);
}

__device__ __forceinline__ void read_frags(const unsigned short* bufA,
                                           const unsigned short* bufB,
                                           int aoff0, int boff0,
                                           short8 (&fa)[8], short8 (&fb)[4]) {
#pragma unroll
  for (int ni = 0; ni < 4; ++ni)
    fb[ni] = *(const short8*)(bufB + boff0 + ni * 512);
#pragma unroll
  for (int mi = 0; mi < 8; ++mi)
    fa[mi] = *(const short8*)(bufA + aoff0 + mi * 512);
}

__device__ __forceinline__ void mfma32(const short8 (&fa)[8],
                                       const short8 (&fb)[4],
                                       f32x4 (&acc)[8][4]) {
  __builtin_amdgcn_s_setprio(1);
#pragma unroll
  for (int mi = 0; mi < 8; ++mi)
#pragma unroll
    for (int ni = 0; ni < 4; ++ni)
      acc[mi][ni] = __builtin_amdgcn_mfma_f32_16x16x32_bf16(
          fa[mi], fb[ni], acc[mi][ni], 0, 0, 0);
  __builtin_amdgcn_s_setprio(0);
}

__global__ __launch_bounds__(512, 2) void score_gemm2_kernel(
    const unsigned short* __restrict__ hsb,
    const unsigned short* __restrict__ Wsb,
    const float* __restrict__ cvec,
    const float* __restrict__ We_w,
    float* __restrict__ score_part) {
  extern __shared__ unsigned short dynls[];  // [A:4x8192][B:4x8192] = 128 KiB
  unsigned short* lA = dynls;
  unsigned short* lB = dynls + 32768;
  __shared__ float scorebuf[4][256];

  const int tid = threadIdx.x;
  const int lane = tid & 63;
  const int wave = tid >> 6;
  const int wm = wave >> 2;  // 0..1 : 128-row half
  const int wn = wave & 3;   // 0..3 : 64-col slice
  const int l15 = lane & 15;
  const int lg = lane >> 4;

  // XCD-chunked swizzle (1024 % 8 == 0 -> bijective)
  int d = blockIdx.x;
  int tileid = (d & 7) * 128 + (d >> 3);
  const int mtile = tileid >> 2;
  const int nc = tileid & 3;
  const int m0 = mtile * 256;
  const int n0 = nc * 256;
  const int b = m0 >> 12;

  // staging source pointers (pre-swizzled columns)
  const int r0 = tid >> 2;
  const int r1 = 128 + r0;
  const int sp = tid & 3;
  const int c0 = (sp ^ ((r0 >> 1) & 3)) * 8;
  const int c1 = (sp ^ ((r1 >> 1) & 3)) * 8;
  const unsigned short* pA0 = hsb + (size_t)(m0 + r0) * D_DIM + c0;
  const unsigned short* pA1 = hsb + (size_t)(m0 + r1) * D_DIM + c1;
  const unsigned short* pB0 = Wsb + (size_t)(n0 + r0) * D_DIM + c0;
  const unsigned short* pB1 = Wsb + (size_t)(n0 + r1) * D_DIM + c1;

  // fragment base offsets; XOR slot is invariant across mi/ni (16-row steps)
  const int arow0 = wm * 128 + l15;
  const int aoff0 = arow0 * 32 + (lg ^ ((arow0 >> 1) & 3)) * 8;
  const int brow0 = wn * 64 + l15;
  const int boff0 = brow0 * 32 + (lg ^ ((brow0 >> 1) & 3)) * 8;

  f32x4 acc[8][4];
#pragma unroll
  for (int i = 0; i < 8; ++i)
#pragma unroll
    for (int j = 0; j < 4; ++j) acc[i][j] = (f32x4){0.f, 0.f, 0.f, 0.f};

  short8 fa0[8], fb0[4], fa1[8], fb1[4];

  // prologue: 3 tiles in flight; tiles 0,1 landed before first reads
  issue_tile(0, tid, lA, lB, pA0, pA1, pB0, pB1);
  issue_tile(1, tid, lA, lB, pA0, pA1, pB0, pB1);
  issue_tile(2, tid, lA, lB, pA0, pA1, pB0, pB1);
  WAITV(4);
  BAR();
  read_frags(lA, lB, aoff0, boff0, fa0, fb0);  // tile 0 (buf 0)

  for (int kt = 0; kt < NT - 4; kt += 2) {
    // phase A: compute tile kt, prefetch frags of kt+1, stage kt+3
    issue_tile(kt + 3, tid, lA, lB, pA0, pA1, pB0, pB1);
    {
      int bq = ((kt + 1) & 3) * 8192;
      read_frags(lA + bq, lB + bq, aoff0, boff0, fa1, fb1);
    }
    mfma32(fa0, fb0, acc);
    WAITV(4);  // tile kt+2 landed
    BAR();
    // phase B: compute tile kt+1, prefetch frags of kt+2, stage kt+4
    issue_tile(kt + 4, tid, lA, lB, pA0, pA1, pB0, pB1);
    {
      int bq = ((kt + 2) & 3) * 8192;
      read_frags(lA + bq, lB + bq, aoff0, boff0, fa0, fb0);
    }
    mfma32(fa1, fb1, acc);
    WAITV(4);  // tile kt+3 landed
    BAR();
  }
  // tail: fa0/fb0 = tile NT-4 (28); tiles 29,30 landed/issued; 31 not issued
  issue_tile(NT - 1, tid, lA, lB, pA0, pA1, pB0, pB1);
  {
    int bq = ((NT - 3) & 3) * 8192;
    read_frags(lA + bq, lB + bq, aoff0, boff0, fa1, fb1);  // tile 29
  }
  mfma32(fa0, fb0, acc);  // tile 28
  WAITV(4);               // tile 30 landed
  BAR();
  {
    int bq = ((NT - 2) & 3) * 8192;
    read_frags(lA + bq, lB + bq, aoff0, boff0, fa0, fb0);  // tile 30
  }
  mfma32(fa1, fb1, acc);  // tile 29
  WAITV(0);               // tile 31 landed
  BAR();
  {
    int bq = ((NT - 1) & 3) * 8192;
    read_frags(lA + bq, lB + bq, aoff0, boff0, fa1, fb1);  // tile 31
  }
  mfma32(fa0, fb0, acc);  // tile 30
  mfma32(fa1, fb1, acc);  // tile 31

  // epilogue: tanh(acc + c)*We, reduce over this block's 256 columns
  float chv[4], whv[4];
#pragma unroll
  for (int ni = 0; ni < 4; ++ni) {
    int h = n0 + wn * 64 + ni * 16 + l15;
    chv[ni] = cvec[b * H_DIM + h];
    whv[ni] = We_w[h];
  }
#pragma unroll
  for (int mi = 0; mi < 8; ++mi)
#pragma unroll
    for (int r = 0; r < 4; ++r) {
      float s = 0.f;
#pragma unroll
      for (int ni = 0; ni < 4; ++ni)
        s += tanh_fast(acc[mi][ni][r] + chv[ni]) * whv[ni];
      s += __shfl_xor(s, 1);
      s += __shfl_xor(s, 2);
      s += __shfl_xor(s, 4);
      s += __shfl_xor(s, 8);
      if (l15 == 0) scorebuf[wn][wm * 128 + mi * 16 + lg * 4 + r] = s;
    }
  __syncthreads();
  if (tid < 256) {
    float s = scorebuf[0][tid] + scorebuf[1][tid] + scorebuf[2][tid] +
              scorebuf[3][tid];
    score_part[(size_t)nc * M_TOT + m0 + tid] = s;
  }
}

// ---------- fallback GEMM (round-1 structure, fp32 A in-kernel cvt) ----------
__global__ __launch_bounds__(256) void score_gemm_fp32_kernel(
    const float* __restrict__ hs,
    const unsigned short* __restrict__ Wsb,
    const float* __restrict__ cvec,
    const float* __restrict__ We_w,
    float* __restrict__ score_part) {
  __shared__ __align__(16) unsigned short lA[128 * 64];
  __shared__ __align__(16) unsigned short lB[128 * 64];
  __shared__ float scorebuf[2][128];

  const int tid = threadIdx.x;
  const int lane = tid & 63;
  const int wave = tid >> 6;
  const int wr = wave >> 1;
  const int wc = wave & 1;
  const int mtile = blockIdx.x;
  const int gy = blockIdx.y;
  const int m0 = mtile * 128;
  const int b = mtile >> 5;
  const int l15 = lane & 15;
  const int lg = lane >> 4;

  float rowsum[4][4];
#pragma unroll
  for (int i = 0; i < 4; ++i)
#pragma unroll
    for (int j = 0; j < 4; ++j) rowsum[i][j] = 0.f;

  for (int ncq = gy * 4; ncq < gy * 4 + 4; ++ncq) {
    const int n0 = ncq * 128;
    f32x4 acc[4][4];
#pragma unroll
    for (int i = 0; i < 4; ++i)
#pragma unroll
      for (int j = 0; j < 4; ++j) acc[i][j] = (f32x4){0.f, 0.f, 0.f, 0.f};

    for (int k0 = 0; k0 < D_DIM; k0 += 64) {
#pragma unroll
      for (int r = 0; r < 4; ++r) {
        int s = tid + r * 256;
        int row = s >> 3, sl = s & 7;
        int src = sl ^ (row & 7);
        gload_lds16(&lB[s * 8], Wsb + (size_t)(n0 + row) * D_DIM + k0 + src * 8);
      }
      float4 a0[4], a1[4];
#pragma unroll
      for (int r = 0; r < 4; ++r) {
        int s = tid + r * 256;
        int row = s >> 3, sl = s & 7;
        int src = sl ^ (row & 7);
        const float* ga = hs + (size_t)(m0 + row) * D_DIM + k0 + src * 8;
        a0[r] = *(const float4*)ga;
        a1[r] = *(const float4*)(ga + 4);
      }
#pragma unroll
      for (int r = 0; r < 4; ++r) {
        int s = tid + r * 256;
        union { unsigned short us[8]; short8 v; } pk;
        pk.us[0] = f2bf(a0[r].x); pk.us[1] = f2bf(a0[r].y);
        pk.us[2] = f2bf(a0[r].z); pk.us[3] = f2bf(a0[r].w);
        pk.us[4] = f2bf(a1[r].x); pk.us[5] = f2bf(a1[r].y);
        pk.us[6] = f2bf(a1[r].z); pk.us[7] = f2bf(a1[r].w);
        *(short8*)(&lA[s * 8]) = pk.v;
      }
      __syncthreads();
#pragma unroll
      for (int kf = 0; kf < 2; ++kf) {
        short8 af[4], bfr[4];
        int cgrp = kf * 4 + lg;
#pragma unroll
        for (int mi = 0; mi < 4; ++mi) {
          int row = wr * 64 + mi * 16 + l15;
          af[mi] = *(const short8*)&lA[row * 64 + (cgrp ^ (row & 7)) * 8];
        }
#pragma unroll
        for (int ni = 0; ni < 4; ++ni) {
          int row = wc * 64 + ni * 16 + l15;
          bfr[ni] = *(const short8*)&lB[row * 64 + (cgrp ^ (row & 7)) * 8];
        }
#pragma unroll
        for (int mi = 0; mi < 4; ++mi)
#pragma unroll
          for (int ni = 0; ni < 4; ++ni)
            acc[mi][ni] = __builtin_amdgcn_mfma_f32_16x16x32_bf16(
                af[mi], bfr[ni], acc[mi][ni], 0, 0, 0);
      }
      __syncthreads();
    }
#pragma unroll
    for (int ni = 0; ni < 4; ++ni) {
      int h = n0 + wc * 64 + ni * 16 + l15;
      float ch = cvec[b * H_DIM + h];
      float wh = We_w[h];
#pragma unroll
      for (int mi = 0; mi < 4; ++mi)
#pragma unroll
        for (int r2 = 0; r2 < 4; ++r2)
          rowsum[mi][r2] += tanh_fast(acc[mi][ni][r2] + ch) * wh;
    }
  }
#pragma unroll
  for (int mi = 0; mi < 4; ++mi)
#pragma unroll
    for (int r2 = 0; r2 < 4; ++r2) {
      float v = rowsum[mi][r2];
      v += __shfl_xor(v, 1);
      v += __shfl_xor(v, 2);
      v += __shfl_xor(v, 4);
      v += __shfl_xor(v, 8);
      rowsum[mi][r2] = v;
    }
  if (l15 == 0) {
#pragma unroll
    for (int mi = 0; mi < 4; ++mi)
#pragma unroll
      for (int r2 = 0; r2 < 4; ++r2)
        scorebuf[wc][wr * 64 + mi * 16 + lg * 4 + r2] = rowsum[mi][r2];
  }
  __syncthreads();
  if (tid < 128) {
    score_part[(size_t)gy * M_TOT + m0 + tid] =
        scorebuf[0][tid] + scorebuf[1][tid];
  }
}

// ---------- softmax over S with rel-position bias ----------
__global__ void softmax_kernel(const float* __restrict__ part,
                               const int* __restrict__ hs_i,
                               const int* __restrict__ ht_i,
                               const float* __restrict__ emb,
                               const float* __restrict__ lam,
                               float* __restrict__ wout, int nparts) {
  int b = blockIdx.x;
  int tid = threadIdx.x;
  float lam0 = lam[0], lam1 = lam[1], lam2 = lam[2];
  int tk = ht_i[b];
  float xs[16];
  float mx = -1e30f;
#pragma unroll
  for (int i = 0; i < 16; ++i) {
    int s = tid + i * 256;
    size_t m = (size_t)b * S_LEN + s;
    float x = 0.f;
    for (int g = 0; g < nparts; ++g) x += part[(size_t)g * M_TOT + m];
    int idx = hs_i[m] * 512 + tk;
    const float* e = emb + (size_t)idx * 3;
    x += e[0] * lam0 + e[1] * lam1 + e[2] * lam2;
    xs[i] = x;
    mx = fmaxf(mx, x);
  }
  __shared__ float redm[4];
  __shared__ float reds[4];
#pragma unroll
  for (int off = 32; off >= 1; off >>= 1) mx = fmaxf(mx, __shfl_xor(mx, off));
  if ((tid & 63) == 0) redm[tid >> 6] = mx;
  __syncthreads();
  mx = fmaxf(fmaxf(redm[0], redm[1]), fmaxf(redm[2], redm[3]));
  float sum = 0.f;
#pragma unroll
  for (int i = 0; i < 16; ++i) {
    xs[i] = __expf(xs[i] - mx);
    sum += xs[i];
  }
#pragma unroll
  for (int off = 32; off >= 1; off >>= 1) sum += __shfl_xor(sum, off);
  if ((tid & 63) == 0) reds[tid >> 6] = sum;
  __syncthreads();
  sum = reds[0] + reds[1] + reds[2] + reds[3];
  float inv = 1.0f / sum;
#pragma unroll
  for (int i = 0; i < 16; ++i)
    wout[(size_t)b * S_LEN + tid + i * 256] = xs[i] * inv;
}

// ---------- wsum (bf16 input) ----------
__global__ void wsum_bf16_kernel(const unsigned short* __restrict__ hsb,
                                 const float* __restrict__ w,
                                 float* __restrict__ u) {
  int bx = blockIdx.x;
  int b = bx >> 5;
  int sc = bx & 31;
  int tid = threadIdx.x;
  int dcol = tid * 4;
  int s0 = sc * 128;
  const unsigned short* base = hsb + ((size_t)b * S_LEN + s0) * D_DIM + dcol;
  const float* wrow = w + (size_t)b * S_LEN + s0;
  float4 acc = {0.f, 0.f, 0.f, 0.f};
#pragma unroll 4
  for (int i = 0; i < 128; ++i) {
    float ww = wrow[i];
    ushort2 v01 = *(const ushort2*)(base + (size_t)i * D_DIM);
    ushort2 v23 = *(const ushort2*)(base + (size_t)i * D_DIM + 2);
    acc.x += ww * __uint_as_float((unsigned int)v01.x << 16);
    acc.y += ww * __uint_as_float((unsigned int)v01.y << 16);
    acc.z += ww * __uint_as_float((unsigned int)v23.x << 16);
    acc.w += ww * __uint_as_float((unsigned int)v23.y << 16);
  }
  atomicAdd(&u[b * D_DIM + dcol + 0], acc.x);
  atomicAdd(&u[b * D_DIM + dcol + 1], acc.y);
  atomicAdd(&u[b * D_DIM + dcol + 2], acc.z);
  atomicAdd(&u[b * D_DIM + dcol + 3], acc.w);
}

// ---------- wsum (fp32 fallback) ----------
__global__ void wsum_kernel(const float* __restrict__ hs,
                            const float* __restrict__ w,
                            float* __restrict__ u) {
  int bx = blockIdx.x;
  int b = bx >> 5;
  int sc = bx & 31;
  int tid = threadIdx.x;
  int dcol = tid * 4;
  int s0 = sc * 128;
  const float* base = hs + ((size_t)b * S_LEN + s0) * D_DIM + dcol;
  const float* wrow = w + (size_t)b * S_LEN + s0;
  float4 acc = {0.f, 0.f, 0.f, 0.f};
#pragma unroll 4
  for (int i = 0; i < 128; ++i) {
    float ww = wrow[i];
    float4 v = *(const float4*)(base + (size_t)i * D_DIM);
    acc.x += ww * v.x;
    acc.y += ww * v.y;
    acc.z += ww * v.z;
    acc.w += ww * v.w;
  }
  atomicAdd(&u[b * D_DIM + dcol + 0], acc.x);
  atomicAdd(&u[b * D_DIM + dcol + 1], acc.y);
  atomicAdd(&u[b * D_DIM + dcol + 2], acc.z);
  atomicAdd(&u[b * D_DIM + dcol + 3], acc.w);
}

// ---------- alpha[b,h] = u[b]·Ws_w[h] + Ws_b[h] ----------
__global__ void alpha_kernel(const float* __restrict__ u,
                             const float* __restrict__ Ws_w,
                             const float* __restrict__ Ws_b,
                             float* __restrict__ out) {
  int gw = blockIdx.x * 4 + (threadIdx.x >> 6);
  int lane = threadIdx.x & 63;
  int b = gw >> 10;
  int h = gw & 1023;
  const float* ur = u + b * D_DIM;
  const float* wrow = Ws_w + (size_t)h * D_DIM;
  float acc = 0.f;
#pragma unroll
  for (int i = 0; i < 4; ++i) {
    int dcol = lane * 4 + i * 256;
    float4 x = *(const float4*)(ur + dcol);
    float4 y = *(const float4*)(wrow + dcol);
    acc += x.x * y.x + x.y * y.y + x.z * y.z + x.w * y.w;
  }
#pragma unroll
  for (int off = 32; off >= 1; off >>= 1) acc += __shfl_xor(acc, off);
  if (lane == 0) out[b * H_DIM + h] = acc + Ws_b[h];
}

extern "C" void kernel_launch(void* const* d_in, const int* in_sizes, int n_in,
                              void* d_out, int out_size, void* d_ws,
                              size_t ws_size, hipStream_t stream) {
  const float* hs = (const float*)d_in[0];
  const float* ht_k = (const float*)d_in[1];
  const float* hm_k = (const float*)d_in[2];
  const float* Ws_w = (const float*)d_in[3];
  const float* Ws_b = (const float*)d_in[4];
  const float* Wt_w = (const float*)d_in[5];
  const float* Wt_b = (const float*)d_in[6];
  const float* Wr_w = (const float*)d_in[7];
  const float* Wr_b = (const float*)d_in[8];
  const float* We_w = (const float*)d_in[9];
  const float* emb = (const float*)d_in[11];
  const float* lam = (const float*)d_in[12];
  const int* hs_i = (const int*)d_in[13];
  const int* ht_i = (const int*)d_in[14];
  float* out = (float*)d_out;

  const size_t HSB = (size_t)M_TOT * D_DIM * 2;  // 128 MB
  const size_t FAST_NEEDED = HSB + 2097152 + 1048576 + 262144 + 65536 + 65536;

  char* ws = (char*)d_ws;
  if (ws_size >= FAST_NEEDED) {
    unsigned short* hsb = (unsigned short*)ws;
    unsigned short* Wsb = (unsigned short*)(ws + HSB);
    float* part = (float*)(ws + HSB + 2097152);
    float* wgt = (float*)(ws + HSB + 2097152 + 1048576);
    float* u = (float*)(ws + HSB + 2097152 + 1048576 + 262144);
    float* cvec = (float*)(ws + HSB + 2097152 + 1048576 + 262144 + 65536);

    hipFuncSetAttribute((const void*)score_gemm2_kernel,
                        hipFuncAttributeMaxDynamicSharedMemorySize, 131072);

    cvt_hs_kernel<<<32768, 256, 0, stream>>>(hs, hsb);
    cvt_w_kernel<<<512, 256, 0, stream>>>(Ws_w, Wsb);
    prep_c_kernel<<<4096, 256, 0, stream>>>(ht_k, hm_k, Wt_w, Wt_b, Wr_w,
                                            Wr_b, cvec);
    score_gemm2_kernel<<<1024, 512, 131072, stream>>>(hsb, Wsb, cvec, We_w,
                                                      part);
    softmax_kernel<<<16, 256, 0, stream>>>(part, hs_i, ht_i, emb, lam, wgt, 4);
    hipMemsetAsync(u, 0, B_SZ * D_DIM * sizeof(float), stream);
    wsum_bf16_kernel<<<512, 256, 0, stream>>>(hsb, wgt, u);
    alpha_kernel<<<4096, 256, 0, stream>>>(u, Ws_w, Ws_b, out);
    return;
  }

  // fallback: small-ws path
  unsigned short* Wsb = (unsigned short*)(ws);
  float* cvec = (float*)(ws + 2097152);
  float* part = (float*)(ws + 2097152 + 65536);
  float* wgt = (float*)(ws + 2097152 + 65536 + 524288);
  float* u = (float*)(ws + 2097152 + 65536 + 524288 + 262144);

  cvt_w_kernel<<<512, 256, 0, stream>>>(Ws_w, Wsb);
  prep_c_kernel<<<4096, 256, 0, stream>>>(ht_k, hm_k, Wt_w, Wt_b, Wr_w, Wr_b,
                                          cvec);
  dim3 g2(512, 2);
  score_gemm_fp32_kernel<<<g2, 256, 0, stream>>>(hs, Wsb, cvec, We_w, part);
  softmax_kernel<<<16, 256, 0, stream>>>(part, hs_i, ht_i, emb, lam, wgt, 2);
  hipMemsetAsync(u, 0, B_SZ * D_DIM * sizeof(float), stream);
  wsum_kernel<<<512, 256, 0, stream>>>(hs, wgt, u);
  alpha_kernel<<<4096, 256, 0, stream>>>(u, Ws_w, Ws_b, out);
}

// Round 5
// 288.478 us; speedup vs baseline: 1.3883x; 1.0374x over previous
//
#include <hip/hip_runtime.h>
#include <hip/hip_bf16.h>
#include <cstdint>
#include <cstddef>

typedef __attribute__((ext_vector_type(4))) float f32x4;
typedef __attribute__((ext_vector_type(8))) short short8;

#define S_LEN 4096
#define D_DIM 1024
#define H_DIM 1024
#define B_SZ  16
#define M_TOT (B_SZ * S_LEN)  // 65536

// ---------- helpers ----------
__device__ __forceinline__ unsigned short f2bf(float f) {
  unsigned int u = __float_as_uint(f);
  u += 0x7fffu + ((u >> 16) & 1u);
  return (unsigned short)(u >> 16);
}

__device__ __forceinline__ void gload_lds16(void* lds, const void* g) {
  __builtin_amdgcn_global_load_lds(
      (const __attribute__((address_space(1))) unsigned int*)g,
      (__attribute__((address_space(3))) unsigned int*)lds, 16, 0, 0);
}

__device__ __forceinline__ float tanh_fast(float x) {
  return 1.0f - 2.0f / (1.0f + __expf(2.0f * x));
}

#define BAR() __builtin_amdgcn_s_barrier()
#define LGKM0()                                            \
  do {                                                     \
    asm volatile("s_waitcnt lgkmcnt(0)" ::: "memory");     \
    __builtin_amdgcn_sched_barrier(0);                     \
  } while (0)

// ---------- kernel 0: hs fp32 -> bf16 ----------
__global__ void cvt_hs_kernel(const float* __restrict__ w,
                              unsigned short* __restrict__ o) {
  size_t i = ((size_t)blockIdx.x * 256 + threadIdx.x) * 8;
  float4 v0 = *(const float4*)(w + i);
  float4 v1 = *(const float4*)(w + i + 4);
  union { unsigned short us[8]; short8 v; } pk;
  pk.us[0] = f2bf(v0.x); pk.us[1] = f2bf(v0.y);
  pk.us[2] = f2bf(v0.z); pk.us[3] = f2bf(v0.w);
  pk.us[4] = f2bf(v1.x); pk.us[5] = f2bf(v1.y);
  pk.us[6] = f2bf(v1.z); pk.us[7] = f2bf(v1.w);
  *(short8*)(o + i) = pk.v;
}

// ---------- kernel 1: Ws_w fp32 -> bf16 ----------
__global__ void cvt_w_kernel(const float* __restrict__ w,
                             unsigned short* __restrict__ o) {
  int i = (blockIdx.x * 256 + threadIdx.x) * 8;
  float4 v0 = *(const float4*)(w + i);
  float4 v1 = *(const float4*)(w + i + 4);
  union { unsigned short us[8]; short8 v; } pk;
  pk.us[0] = f2bf(v0.x); pk.us[1] = f2bf(v0.y);
  pk.us[2] = f2bf(v0.z); pk.us[3] = f2bf(v0.w);
  pk.us[4] = f2bf(v1.x); pk.us[5] = f2bf(v1.y);
  pk.us[6] = f2bf(v1.z); pk.us[7] = f2bf(v1.w);
  *(short8*)(o + i) = pk.v;
}

// ---------- kernel 2: c[b,h] ----------
__global__ void prep_c_kernel(const float* __restrict__ ht,
                              const float* __restrict__ hm,
                              const float* __restrict__ Wt_w,
                              const float* __restrict__ Wt_b,
                              const float* __restrict__ Wr_w,
                              const float* __restrict__ Wr_b,
                              float* __restrict__ cvec) {
  int gw = blockIdx.x * 4 + (threadIdx.x >> 6);
  int lane = threadIdx.x & 63;
  int b = gw >> 10;
  int h = gw & 1023;
  const float* a1 = ht + b * D_DIM;
  const float* w1 = Wt_w + (size_t)h * D_DIM;
  const float* a2 = hm + b * H_DIM;
  const float* w2 = Wr_w + (size_t)h * H_DIM;
  float acc = 0.f;
#pragma unroll
  for (int i = 0; i < 4; ++i) {
    int d = lane * 4 + i * 256;
    float4 x1 = *(const float4*)(a1 + d);
    float4 y1 = *(const float4*)(w1 + d);
    float4 x2 = *(const float4*)(a2 + d);
    float4 y2 = *(const float4*)(w2 + d);
    acc += x1.x * y1.x + x1.y * y1.y + x1.z * y1.z + x1.w * y1.w;
    acc += x2.x * y2.x + x2.y * y2.y + x2.z * y2.z + x2.w * y2.w;
  }
#pragma unroll
  for (int off = 32; off >= 1; off >>= 1) acc += __shfl_xor(acc, off);
  if (lane == 0) cvec[b * H_DIM + h] = acc + Wt_b[h] + Wr_b[h];
}

// ---------- 256x256 8-phase fused GEMM (m201-style schedule) ----------
// BK=64, 16 K-steps. LDS: lA[2][256][64] + lB[2][256][64] bf16 = 128 KiB.
// Swizzle: 8 slots of 16B per 128B row; phys_slot = log_slot ^ (row&7),
// applied at stage (pre-swizzled global col) and at ds_read (same XOR).
#define STG_A(nb, h, ss)                                                  \
  do {                                                                    \
    gload_lds16(lA + (nb)*16384 + (h)*8192 + dst0,                        \
                gA + (h)*131072 + (ss)*64);                               \
    gload_lds16(lA + (nb)*16384 + (h)*8192 + dst1,                        \
                gA + (h)*131072 + 65536 + (ss)*64);                       \
  } while (0)
#define STG_B(nb, h, ss)                                                  \
  do {                                                                    \
    gload_lds16(lB + (nb)*16384 + (h)*8192 + dst0,                        \
                gB + (h)*131072 + (ss)*64);                               \
    gload_lds16(lB + (nb)*16384 + (h)*8192 + dst1,                        \
                gB + (h)*131072 + 65536 + (ss)*64);                       \
  } while (0)

#define RDA_LO(OFF)                                                       \
  { _Pragma("unroll") for (int mi = 0; mi < 4; ++mi)                      \
      fa[mi] = *(const short8*)(bA + (OFF) + mi * 1024); }
#define RDA_HI(OFF)                                                       \
  { _Pragma("unroll") for (int mi = 0; mi < 4; ++mi)                      \
      fa[mi] = *(const short8*)(bA + (OFF) + 4096 + mi * 1024); }
#define RDB(FB, OFF)                                                      \
  { _Pragma("unroll") for (int ni = 0; ni < 4; ++ni)                      \
      FB[ni] = *(const short8*)(bB + (OFF) + ni * 1024); }

#define MM16(MIB, FB)                                                     \
  {                                                                       \
    __builtin_amdgcn_s_setprio(1);                                        \
    _Pragma("unroll") for (int mi = 0; mi < 4; ++mi) {                    \
      _Pragma("unroll") for (int ni = 0; ni < 4; ++ni) {                  \
        acc[(MIB) + mi][ni] = __builtin_amdgcn_mfma_f32_16x16x32_bf16(    \
            fa[mi], FB[ni], acc[(MIB) + mi][ni], 0, 0, 0);                \
      }                                                                   \
    }                                                                     \
    __builtin_amdgcn_s_setprio(0);                                        \
  }

__global__ __launch_bounds__(512, 2) void score_gemm3_kernel(
    const unsigned short* __restrict__ hsb,
    const unsigned short* __restrict__ Wsb,
    const float* __restrict__ cvec,
    const float* __restrict__ We_w,
    float* __restrict__ score_part) {
  extern __shared__ unsigned short dynls[];
  unsigned short* lA = dynls;            // [2][16384] elements
  unsigned short* lB = dynls + 32768;
  __shared__ float scorebuf[4][256];

  const int tid = threadIdx.x;
  const int lane = tid & 63;
  const int wave = tid >> 6;
  const int wm = wave >> 2;  // 0..1 : 128-row half
  const int wn = wave & 3;   // 0..3 : 64-col slice
  const int l15 = lane & 15;
  const int lg = lane >> 4;

  // XCD-chunked bijective swizzle (1024 % 8 == 0)
  int d = blockIdx.x;
  int tileid = (d & 7) * 128 + (d >> 3);
  const int mtile = tileid >> 2;
  const int nc = tileid & 3;
  const int m0 = mtile * 256;
  const int n0 = nc * 256;
  const int b = m0 >> 12;

  // staging geometry: thread t stages row (h*128 + j*64 + t>>3), phys slot t&7
  const int tr = tid >> 3;
  const int tc = tid & 7;
  const int scol = ((tc ^ (tr & 7)) << 3);  // pre-swizzled source col
  const unsigned short* gA = hsb + (size_t)(m0 + tr) * 1024 + scol;
  const unsigned short* gB = Wsb + (size_t)(n0 + tr) * 1024 + scol;
  const int dst0 = tid * 8;
  const int dst1 = 4096 + tid * 8;

  // fragment read bases (elements), same XOR as staging
  const int aoff0 = (wm * 128 + l15) * 64 + ((lg ^ (l15 & 7)) << 3);
  const int aoff1 = (wm * 128 + l15) * 64 + (((4 + lg) ^ (l15 & 7)) << 3);
  const int boff0 = (wn * 64 + l15) * 64 + ((lg ^ (l15 & 7)) << 3);
  const int boff1 = (wn * 64 + l15) * 64 + (((4 + lg) ^ (l15 & 7)) << 3);

  f32x4 acc[8][4];
#pragma unroll
  for (int i = 0; i < 8; ++i)
#pragma unroll
    for (int j = 0; j < 4; ++j) acc[i][j] = (f32x4){0.f, 0.f, 0.f, 0.f};

  // prologue: stage K-step 0 into buf 0
  STG_A(0, 0, 0);
  STG_A(0, 1, 0);
  STG_B(0, 0, 0);
  STG_B(0, 1, 0);
  asm volatile("s_waitcnt vmcnt(0)" ::: "memory");
  BAR();

#pragma unroll 2
  for (int s = 0; s < 16; ++s) {
    const unsigned short* bA = lA + (s & 1) * 16384;
    const unsigned short* bB = lB + (s & 1) * 16384;
    const int nb = (s & 1) ^ 1;
    const bool st = (s < 15);
    short8 fa[4], fb0[4], fb1[4];
    // ---- phase 0: A-lo kk0 + B kk0 reads; stage A-half0(s+1)
    RDA_LO(aoff0);
    RDB(fb0, boff0);
    if (st) STG_A(nb, 0, s + 1);
    BAR();
    LGKM0();
    MM16(0, fb0);
    BAR();
    // ---- phase 1: A-hi kk0; stage A-half1(s+1)
    RDA_HI(aoff0);
    if (st) STG_A(nb, 1, s + 1);
    BAR();
    LGKM0();
    MM16(4, fb0);
    BAR();
    // ---- phase 2: A-lo kk1 + B kk1; stage B-half0(s+1)
    RDA_LO(aoff1);
    RDB(fb1, boff1);
    if (st) STG_B(nb, 0, s + 1);
    BAR();
    LGKM0();
    MM16(0, fb1);
    BAR();
    // ---- phase 3: A-hi kk1; stage B-half1(s+1); certify s+1 before its ph0
    RDA_HI(aoff1);
    if (st) STG_B(nb, 1, s + 1);
    BAR();
    LGKM0();
    MM16(4, fb1);
    asm volatile("s_waitcnt vmcnt(0)" ::: "memory");
    BAR();
  }

  // epilogue: tanh(acc + c)*We, reduce over this block's 256 columns
  float chv[4], whv[4];
#pragma unroll
  for (int ni = 0; ni < 4; ++ni) {
    int h = n0 + wn * 64 + ni * 16 + l15;
    chv[ni] = cvec[b * H_DIM + h];
    whv[ni] = We_w[h];
  }
#pragma unroll
  for (int mi = 0; mi < 8; ++mi)
#pragma unroll
    for (int r = 0; r < 4; ++r) {
      float s = 0.f;
#pragma unroll
      for (int ni = 0; ni < 4; ++ni)
        s += tanh_fast(acc[mi][ni][r] + chv[ni]) * whv[ni];
      s += __shfl_xor(s, 1);
      s += __shfl_xor(s, 2);
      s += __shfl_xor(s, 4);
      s += __shfl_xor(s, 8);
      if (l15 == 0) scorebuf[wn][wm * 128 + mi * 16 + lg * 4 + r] = s;
    }
  __syncthreads();
  if (tid < 256) {
    float s = scorebuf[0][tid] + scorebuf[1][tid] + scorebuf[2][tid] +
              scorebuf[3][tid];
    score_part[(size_t)nc * M_TOT + m0 + tid] = s;
  }
}

// ---------- fallback GEMM (round-1 structure, fp32 A in-kernel cvt) ----------
__global__ __launch_bounds__(256) void score_gemm_fp32_kernel(
    const float* __restrict__ hs,
    const unsigned short* __restrict__ Wsb,
    const float* __restrict__ cvec,
    const float* __restrict__ We_w,
    float* __restrict__ score_part) {
  __shared__ __align__(16) unsigned short lA[128 * 64];
  __shared__ __align__(16) unsigned short lB[128 * 64];
  __shared__ float scorebuf[2][128];

  const int tid = threadIdx.x;
  const int lane = tid & 63;
  const int wave = tid >> 6;
  const int wr = wave >> 1;
  const int wc = wave & 1;
  const int mtile = blockIdx.x;
  const int gy = blockIdx.y;
  const int m0 = mtile * 128;
  const int b = mtile >> 5;
  const int l15 = lane & 15;
  const int lg = lane >> 4;

  float rowsum[4][4];
#pragma unroll
  for (int i = 0; i < 4; ++i)
#pragma unroll
    for (int j = 0; j < 4; ++j) rowsum[i][j] = 0.f;

  for (int ncq = gy * 4; ncq < gy * 4 + 4; ++ncq) {
    const int n0 = ncq * 128;
    f32x4 acc[4][4];
#pragma unroll
    for (int i = 0; i < 4; ++i)
#pragma unroll
      for (int j = 0; j < 4; ++j) acc[i][j] = (f32x4){0.f, 0.f, 0.f, 0.f};

    for (int k0 = 0; k0 < D_DIM; k0 += 64) {
#pragma unroll
      for (int r = 0; r < 4; ++r) {
        int s = tid + r * 256;
        int row = s >> 3, sl = s & 7;
        int src = sl ^ (row & 7);
        gload_lds16(&lB[s * 8], Wsb + (size_t)(n0 + row) * D_DIM + k0 + src * 8);
      }
      float4 a0[4], a1[4];
#pragma unroll
      for (int r = 0; r < 4; ++r) {
        int s = tid + r * 256;
        int row = s >> 3, sl = s & 7;
        int src = sl ^ (row & 7);
        const float* ga = hs + (size_t)(m0 + row) * D_DIM + k0 + src * 8;
        a0[r] = *(const float4*)ga;
        a1[r] = *(const float4*)(ga + 4);
      }
#pragma unroll
      for (int r = 0; r < 4; ++r) {
        int s = tid + r * 256;
        union { unsigned short us[8]; short8 v; } pk;
        pk.us[0] = f2bf(a0[r].x); pk.us[1] = f2bf(a0[r].y);
        pk.us[2] = f2bf(a0[r].z); pk.us[3] = f2bf(a0[r].w);
        pk.us[4] = f2bf(a1[r].x); pk.us[5] = f2bf(a1[r].y);
        pk.us[6] = f2bf(a1[r].z); pk.us[7] = f2bf(a1[r].w);
        *(short8*)(&lA[s * 8]) = pk.v;
      }
      __syncthreads();
#pragma unroll
      for (int kf = 0; kf < 2; ++kf) {
        short8 af[4], bfr[4];
        int cgrp = kf * 4 + lg;
#pragma unroll
        for (int mi = 0; mi < 4; ++mi) {
          int row = wr * 64 + mi * 16 + l15;
          af[mi] = *(const short8*)&lA[row * 64 + (cgrp ^ (row & 7)) * 8];
        }
#pragma unroll
        for (int ni = 0; ni < 4; ++ni) {
          int row = wc * 64 + ni * 16 + l15;
          bfr[ni] = *(const short8*)&lB[row * 64 + (cgrp ^ (row & 7)) * 8];
        }
#pragma unroll
        for (int mi = 0; mi < 4; ++mi)
#pragma unroll
          for (int ni = 0; ni < 4; ++ni)
            acc[mi][ni] = __builtin_amdgcn_mfma_f32_16x16x32_bf16(
                af[mi], bfr[ni], acc[mi][ni], 0, 0, 0);
      }
      __syncthreads();
    }
#pragma unroll
    for (int ni = 0; ni < 4; ++ni) {
      int h = n0 + wc * 64 + ni * 16 + l15;
      float ch = cvec[b * H_DIM + h];
      float wh = We_w[h];
#pragma unroll
      for (int mi = 0; mi < 4; ++mi)
#pragma unroll
        for (int r2 = 0; r2 < 4; ++r2)
          rowsum[mi][r2] += tanh_fast(acc[mi][ni][r2] + ch) * wh;
    }
  }
#pragma unroll
  for (int mi = 0; mi < 4; ++mi)
#pragma unroll
    for (int r2 = 0; r2 < 4; ++r2) {
      float v = rowsum[mi][r2];
      v += __shfl_xor(v, 1);
      v += __shfl_xor(v, 2);
      v += __shfl_xor(v, 4);
      v += __shfl_xor(v, 8);
      rowsum[mi][r2] = v;
    }
  if (l15 == 0) {
#pragma unroll
    for (int mi = 0; mi < 4; ++mi)
#pragma unroll
      for (int r2 = 0; r2 < 4; ++r2)
        scorebuf[wc][wr * 64 + mi * 16 + lg * 4 + r2] = rowsum[mi][r2];
  }
  __syncthreads();
  if (tid < 128) {
    score_part[(size_t)gy * M_TOT + m0 + tid] =
        scorebuf[0][tid] + scorebuf[1][tid];
  }
}

// ---------- softmax over S with rel-position bias ----------
__global__ void softmax_kernel(const float* __restrict__ part,
                               const int* __restrict__ hs_i,
                               const int* __restrict__ ht_i,
                               const float* __restrict__ emb,
                               const float* __restrict__ lam,
                               float* __restrict__ wout, int nparts) {
  int b = blockIdx.x;
  int tid = threadIdx.x;
  float lam0 = lam[0], lam1 = lam[1], lam2 = lam[2];
  int tk = ht_i[b];
  float xs[16];
  float mx = -1e30f;
#pragma unroll
  for (int i = 0; i < 16; ++i) {
    int s = tid + i * 256;
    size_t m = (size_t)b * S_LEN + s;
    float x = 0.f;
    for (int g = 0; g < nparts; ++g) x += part[(size_t)g * M_TOT + m];
    int idx = hs_i[m] * 512 + tk;
    const float* e = emb + (size_t)idx * 3;
    x += e[0] * lam0 + e[1] * lam1 + e[2] * lam2;
    xs[i] = x;
    mx = fmaxf(mx, x);
  }
  __shared__ float redm[4];
  __shared__ float reds[4];
#pragma unroll
  for (int off = 32; off >= 1; off >>= 1) mx = fmaxf(mx, __shfl_xor(mx, off));
  if ((tid & 63) == 0) redm[tid >> 6] = mx;
  __syncthreads();
  mx = fmaxf(fmaxf(redm[0], redm[1]), fmaxf(redm[2], redm[3]));
  float sum = 0.f;
#pragma unroll
  for (int i = 0; i < 16; ++i) {
    xs[i] = __expf(xs[i] - mx);
    sum += xs[i];
  }
#pragma unroll
  for (int off = 32; off >= 1; off >>= 1) sum += __shfl_xor(sum, off);
  if ((tid & 63) == 0) reds[tid >> 6] = sum;
  __syncthreads();
  sum = reds[0] + reds[1] + reds[2] + reds[3];
  float inv = 1.0f / sum;
#pragma unroll
  for (int i = 0; i < 16; ++i)
    wout[(size_t)b * S_LEN + tid + i * 256] = xs[i] * inv;
}

// ---------- wsum (bf16 input) ----------
__global__ void wsum_bf16_kernel(const unsigned short* __restrict__ hsb,
                                 const float* __restrict__ w,
                                 float* __restrict__ u) {
  int bx = blockIdx.x;
  int b = bx >> 5;
  int sc = bx & 31;
  int tid = threadIdx.x;
  int dcol = tid * 4;
  int s0 = sc * 128;
  const unsigned short* base = hsb + ((size_t)b * S_LEN + s0) * D_DIM + dcol;
  const float* wrow = w + (size_t)b * S_LEN + s0;
  float4 acc = {0.f, 0.f, 0.f, 0.f};
#pragma unroll 4
  for (int i = 0; i < 128; ++i) {
    float ww = wrow[i];
    ushort2 v01 = *(const ushort2*)(base + (size_t)i * D_DIM);
    ushort2 v23 = *(const ushort2*)(base + (size_t)i * D_DIM + 2);
    acc.x += ww * __uint_as_float((unsigned int)v01.x << 16);
    acc.y += ww * __uint_as_float((unsigned int)v01.y << 16);
    acc.z += ww * __uint_as_float((unsigned int)v23.x << 16);
    acc.w += ww * __uint_as_float((unsigned int)v23.y << 16);
  }
  atomicAdd(&u[b * D_DIM + dcol + 0], acc.x);
  atomicAdd(&u[b * D_DIM + dcol + 1], acc.y);
  atomicAdd(&u[b * D_DIM + dcol + 2], acc.z);
  atomicAdd(&u[b * D_DIM + dcol + 3], acc.w);
}

// ---------- wsum (fp32 fallback) ----------
__global__ void wsum_kernel(const float* __restrict__ hs,
                            const float* __restrict__ w,
                            float* __restrict__ u) {
  int bx = blockIdx.x;
  int b = bx >> 5;
  int sc = bx & 31;
  int tid = threadIdx.x;
  int dcol = tid * 4;
  int s0 = sc * 128;
  const float* base = hs + ((size_t)b * S_LEN + s0) * D_DIM + dcol;
  const float* wrow = w + (size_t)b * S_LEN + s0;
  float4 acc = {0.f, 0.f, 0.f, 0.f};
#pragma unroll 4
  for (int i = 0; i < 128; ++i) {
    float ww = wrow[i];
    float4 v = *(const float4*)(base + (size_t)i * D_DIM);
    acc.x += ww * v.x;
    acc.y += ww * v.y;
    acc.z += ww * v.z;
    acc.w += ww * v.w;
  }
  atomicAdd(&u[b * D_DIM + dcol + 0], acc.x);
  atomicAdd(&u[b * D_DIM + dcol + 1], acc.y);
  atomicAdd(&u[b * D_DIM + dcol + 2], acc.z);
  atomicAdd(&u[b * D_DIM + dcol + 3], acc.w);
}

// ---------- alpha[b,h] = u[b]·Ws_w[h] + Ws_b[h] ----------
__global__ void alpha_kernel(const float* __restrict__ u,
                             const float* __restrict__ Ws_w,
                             const float* __restrict__ Ws_b,
                             float* __restrict__ out) {
  int gw = blockIdx.x * 4 + (threadIdx.x >> 6);
  int lane = threadIdx.x & 63;
  int b = gw >> 10;
  int h = gw & 1023;
  const float* ur = u + b * D_DIM;
  const float* wrow = Ws_w + (size_t)h * D_DIM;
  float acc = 0.f;
#pragma unroll
  for (int i = 0; i < 4; ++i) {
    int dcol = lane * 4 + i * 256;
    float4 x = *(const float4*)(ur + dcol);
    float4 y = *(const float4*)(wrow + dcol);
    acc += x.x * y.x + x.y * y.y + x.z * y.z + x.w * y.w;
  }
#pragma unroll
  for (int off = 32; off >= 1; off >>= 1) acc += __shfl_xor(acc, off);
  if (lane == 0) out[b * H_DIM + h] = acc + Ws_b[h];
}

extern "C" void kernel_launch(void* const* d_in, const int* in_sizes, int n_in,
                              void* d_out, int out_size, void* d_ws,
                              size_t ws_size, hipStream_t stream) {
  const float* hs = (const float*)d_in[0];
  const float* ht_k = (const float*)d_in[1];
  const float* hm_k = (const float*)d_in[2];
  const float* Ws_w = (const float*)d_in[3];
  const float* Ws_b = (const float*)d_in[4];
  const float* Wt_w = (const float*)d_in[5];
  const float* Wt_b = (const float*)d_in[6];
  const float* Wr_w = (const float*)d_in[7];
  const float* Wr_b = (const float*)d_in[8];
  const float* We_w = (const float*)d_in[9];
  const float* emb = (const float*)d_in[11];
  const float* lam = (const float*)d_in[12];
  const int* hs_i = (const int*)d_in[13];
  const int* ht_i = (const int*)d_in[14];
  float* out = (float*)d_out;

  const size_t HSB = (size_t)M_TOT * D_DIM * 2;  // 128 MB
  const size_t FAST_NEEDED = HSB + 2097152 + 1048576 + 262144 + 65536 + 65536;

  char* ws = (char*)d_ws;
  if (ws_size >= FAST_NEEDED) {
    unsigned short* hsb = (unsigned short*)ws;
    unsigned short* Wsb = (unsigned short*)(ws + HSB);
    float* part = (float*)(ws + HSB + 2097152);
    float* wgt = (float*)(ws + HSB + 2097152 + 1048576);
    float* u = (float*)(ws + HSB + 2097152 + 1048576 + 262144);
    float* cvec = (float*)(ws + HSB + 2097152 + 1048576 + 262144 + 65536);

    hipFuncSetAttribute((const void*)score_gemm3_kernel,
                        hipFuncAttributeMaxDynamicSharedMemorySize, 131072);

    cvt_hs_kernel<<<32768, 256, 0, stream>>>(hs, hsb);
    cvt_w_kernel<<<512, 256, 0, stream>>>(Ws_w, Wsb);
    prep_c_kernel<<<4096, 256, 0, stream>>>(ht_k, hm_k, Wt_w, Wt_b, Wr_w,
                                            Wr_b, cvec);
    score_gemm3_kernel<<<1024, 512, 131072, stream>>>(hsb, Wsb, cvec, We_w,
                                                      part);
    softmax_kernel<<<16, 256, 0, stream>>>(part, hs_i, ht_i, emb, lam, wgt, 4);
    hipMemsetAsync(u, 0, B_SZ * D_DIM * sizeof(float), stream);
    wsum_bf16_kernel<<<512, 256, 0, stream>>>(hsb, wgt, u);
    alpha_kernel<<<4096, 256, 0, stream>>>(u, Ws_w, Ws_b, out);
    return;
  }

  // fallback: small-ws path
  unsigned short* Wsb = (unsigned short*)(ws);
  float* cvec = (float*)(ws + 2097152);
  float* part = (float*)(ws + 2097152 + 65536);
  float* wgt = (float*)(ws + 2097152 + 65536 + 524288);
  float* u = (float*)(ws + 2097152 + 65536 + 524288 + 262144);

  cvt_w_kernel<<<512, 256, 0, stream>>>(Ws_w, Wsb);
  prep_c_kernel<<<4096, 256, 0, stream>>>(ht_k, hm_k, Wt_w, Wt_b, Wr_w, Wr_b,
                                          cvec);
  dim3 g2(512, 2);
  score_gemm_fp32_kernel<<<g2, 256, 0, stream>>>(hs, Wsb, cvec, We_w, part);
  softmax_kernel<<<16, 256, 0, stream>>>(part, hs_i, ht_i, emb, lam, wgt, 2);
  hipMemsetAsync(u, 0, B_SZ * D_DIM * sizeof(float), stream);
  wsum_kernel<<<512, 256, 0, stream>>>(hs, wgt, u);
  alpha_kernel<<<4096, 256, 0, stream>>>(u, Ws_w, Ws_b, out);
}